// Round 8
// baseline (2819.542 us; speedup 1.0000x reference)
//
#include <hip/hip_runtime.h>
#include <stdint.h>

// Problem constants (fixed by the reference)
#define NN 50000
#define EE 800000
#define INDIM 1280
#define GD 512
#define CAT 1536
#define FC0D 1024
#define FC1D 512
#define OUTD 256
#define NG 64

// contraction split-K geometry: grid = KS * (INDIM/CTS) = 96*8 = 768 = 3 blocks/CU exact
#define KS 96
#define RS 544                  // KS*RS = 52224 >= NN, RS % 32 == 0
#define NPAD (KS * RS)          // 52224
#define QSZ (192 * INDIM)       // 245760
#define CTS 160                 // contract col-tile (8 tiles over 1280)

__device__ __forceinline__ void g2l16(const void* g, void* l) {
    __builtin_amdgcn_global_load_lds(
        (const __attribute__((address_space(1))) void*)g,
        (__attribute__((address_space(3))) void*)l, 16, 0, 0);
}

// ---------------- utility kernels ----------------
__global__ void zero_u32(uint32_t* p, int n) {
    int i = blockIdx.x * 256 + threadIdx.x;
    if (i < n) p[i] = 0u;
}

// count out-degree (by src) for CSR and in-degree (by dst) for dinv
__global__ void hist_edges(const int* __restrict__ ei, int* __restrict__ cnt_s,
                           int* __restrict__ cnt_d) {
    int e = blockIdx.x * 256 + threadIdx.x;
    if (e < EE) {
        atomicAdd(&cnt_s[ei[e]], 1);
        atomicAdd(&cnt_d[ei[EE + e]], 1);
    }
}

// batch is sorted -> per-graph counts via binary search (no atomics)
__global__ void batch_bounds(const int* __restrict__ bat, int* __restrict__ gcnt) {
    int g = threadIdx.x;   // 0..63
    int lo = 0, hi = NN;
    while (lo < hi) {
        int mid = (lo + hi) >> 1;
        if (bat[mid] < g) lo = mid + 1; else hi = mid;
    }
    int nxt = __shfl_down(lo, 1);
    if (g == 63) nxt = NN;
    gcnt[g] = nxt - lo;
}

__global__ __launch_bounds__(1024) void scan1(const int* __restrict__ cnt,
                                              int* __restrict__ row_ptr,
                                              int* __restrict__ bsum, int n) {
    __shared__ int s[1024];
    int tid = threadIdx.x;
    int i = blockIdx.x * 1024 + tid;
    int v = (i < n) ? cnt[i] : 0;
    s[tid] = v;
    __syncthreads();
    for (int off = 1; off < 1024; off <<= 1) {
        int t = 0;
        if (tid >= off) t = s[tid - off];
        __syncthreads();
        if (tid >= off) s[tid] += t;
        __syncthreads();
    }
    if (i < n) row_ptr[i] = s[tid] - v;
    if (tid == 1023) bsum[blockIdx.x] = s[1023];
}

// wave-parallel exclusive scan of nb (<=64) block sums
__global__ void scan2(int* bsum, int nb) {
    int i = threadIdx.x;
    int v = (i < nb) ? bsum[i] : 0;
    int s = v;
#pragma unroll
    for (int off = 1; off < 64; off <<= 1) {
        int t = __shfl_up(s, off);
        if (i >= off) s += t;
    }
    if (i < nb) bsum[i] = s - v;
}

// finalize row_ptr (by src), emit fill and dinv (from in-degree cnt_d)
__global__ __launch_bounds__(1024) void scan3b(int* __restrict__ row_ptr,
                                               const int* __restrict__ bsum,
                                               const int* __restrict__ cnt_d,
                                               float* __restrict__ dinv,
                                               int* __restrict__ fill, int n) {
    int i = blockIdx.x * 1024 + threadIdx.x;
    if (i < n) {
        int rp = row_ptr[i] + bsum[blockIdx.x];
        row_ptr[i] = rp;
        fill[i] = rp;
        dinv[i] = rsqrtf((float)cnt_d[i] + 1.0f);
    }
    if (i == 0) row_ptr[n] = EE;
}

// CSR by src: col[] holds dst
__global__ void scatter_src(const int* __restrict__ ei, int* __restrict__ fill,
                            int* __restrict__ col) {
    int e = blockIdx.x * 256 + threadIdx.x;
    if (e < EE) {
        int s = ei[e];
        int d = ei[EE + e];
        int pos = atomicAdd(&fill[s], 1);
        col[pos] = d;
    }
}

// ---------------- U propagation into packed UU[NPAD][192] ----------------
// (A_hat^T v)[i] = di^2 v[i] + di * sum_{edges (i->j)} dinv[j] * v[j]
// section 0 = U1, 1 = U2, 2 = U3. Pad rows written zero.
__global__ __launch_bounds__(256) void uprop_first(const int* __restrict__ rp,
                                                   const int* __restrict__ col,
                                                   const float* __restrict__ dinv,
                                                   const int* __restrict__ bat,
                                                   float* __restrict__ UU) {
    int wid = threadIdx.x >> 6, lane = threadIdx.x & 63;
    int i = blockIdx.x * 4 + wid;
    if (i >= NPAD) return;
    if (i >= NN) { UU[(size_t)i * 192 + lane] = 0.f; return; }
    float di = dinv[i];
    float acc = (bat[i] == lane) ? di * di : 0.f;
    int s = rp[i], e = rp[i + 1];
    for (int t = s; t < e; t++) {
        int d = col[t];
        float w = di * dinv[d];
        acc += (bat[d] == lane) ? w : 0.f;
    }
    UU[(size_t)i * 192 + lane] = acc;
}

__global__ __launch_bounds__(256) void uprop_next(const int* __restrict__ rp,
                                                  const int* __restrict__ col,
                                                  const float* __restrict__ dinv,
                                                  float* __restrict__ UU,
                                                  int secIn, int secOut) {
    int wid = threadIdx.x >> 6, lane = threadIdx.x & 63;
    int i = blockIdx.x * 4 + wid;
    if (i >= NPAD) return;
    if (i >= NN) { UU[(size_t)i * 192 + secOut * 64 + lane] = 0.f; return; }
    const float* Uin = UU + secIn * 64;
    float di = dinv[i];
    float acc = di * di * Uin[(size_t)i * 192 + lane];
    int s = rp[i], e = rp[i + 1];
    int t = s;
    for (; t + 1 < e; t += 2) {
        int d0 = col[t], d1 = col[t + 1];
        float w0 = di * dinv[d0], w1 = di * dinv[d1];
        float u0 = Uin[(size_t)d0 * 192 + lane];
        float u1 = Uin[(size_t)d1 * 192 + lane];
        acc = fmaf(u0, w0, acc);
        acc = fmaf(u1, w1, acc);
    }
    if (t < e) {
        int d0 = col[t];
        acc = fmaf(Uin[(size_t)d0 * 192 + lane], di * dinv[d0], acc);
    }
    UU[(size_t)i * 192 + secOut * 64 + lane] = acc;
}

// column sums of UU sec0 (U1) and sec1 (U2) -> sigraw[0..63], sigraw[64..127]
__global__ __launch_bounds__(256) void usig_kernel(const float* __restrict__ UU,
                                                   float* __restrict__ sigraw) {
    int g = threadIdx.x & 63, rs = threadIdx.x >> 6;
    int r0 = blockIdx.x * 512;
    int rend = min(r0 + 512, NN);
    float a1 = 0.f, a2 = 0.f;
    for (int r = r0 + rs; r < rend; r += 4) {
        size_t o = (size_t)r * 192 + g;
        a1 += UU[o];
        a2 += UU[o + 64];
    }
    __shared__ float sh[2][256];
    sh[0][threadIdx.x] = a1;
    sh[1][threadIdx.x] = a2;
    __syncthreads();
    if (rs == 0) {
        a1 = sh[0][g] + sh[0][64 + g] + sh[0][128 + g] + sh[0][192 + g];
        a2 = sh[1][g] + sh[1][64 + g] + sh[1][128 + g] + sh[1][192 + g];
        atomicAdd(&sigraw[g], a1);
        atomicAdd(&sigraw[64 + g], a2);
    }
}

// ---------------- contraction: Q = UU^T X  (f32, split-K partials) ----------
// 1-D grid 768 blocks (3/CU exact), XCD-chunked swizzle. Block tile 192g x 160c.
// Thread (tg 0..15: 12 g each, tc 0..15: 10 c each) -> 120 acc (float2[12][5]).
__global__ __launch_bounds__(256, 3) void contract_kernel(
    const float* __restrict__ X, const float* __restrict__ UU,
    float* __restrict__ partial) {
    __shared__ __align__(16) float UUs[32 * 192];   // 24 KB
    __shared__ __align__(16) float Xs[32 * CTS];    // 20 KB
    // bijective XCD-chunk swizzle: 768 = 8 XCD * 96
    const int sbid = (blockIdx.x & 7) * 96 + (blockIdx.x >> 3);
    const int ks = sbid >> 3;        // 0..95
    const int ct = sbid & 7;         // 0..7
    const int tid = threadIdx.x;
    const int tg = tid >> 4;         // 0..15 -> rows tg*12..+11
    const int tc = tid & 15;         // 0..15 -> cols tc*10..+9
    const int r0 = ks * RS;
    const int ctc = ct * CTS;

    float2 acc[12][5];
#pragma unroll
    for (int gg = 0; gg < 12; gg++)
#pragma unroll
        for (int k = 0; k < 5; k++) acc[gg][k] = make_float2(0.f, 0.f);

    // staging geometry (per thread, loop-invariant)
    int uoff[6], xrow[5], xcol[5];
#pragma unroll
    for (int i = 0; i < 6; i++) {
        int p = tid + i * 256;              // 0..1535, 48 segs per 192-f row
        uoff[i] = (p / 48) * 192 + (p % 48) * 4;
    }
#pragma unroll
    for (int i = 0; i < 5; i++) {
        int p = tid + i * 256;              // 0..1279, 40 segs per 160-f row
        xrow[i] = p / 40;
        xcol[i] = (p % 40) * 4;
    }

    for (int ch = 0; ch < RS / 32; ch++) {
        int rb = r0 + ch * 32;
        __syncthreads();
#pragma unroll
        for (int i = 0; i < 6; i++)
            g2l16(UU + (size_t)rb * 192 + uoff[i], (char*)UUs + (tid + i * 256) * 16);
#pragma unroll
        for (int i = 0; i < 5; i++) {
            int xr = rb + xrow[i];
            if (xr >= NN) xr = NN - 1;      // pad rows: UU is zero there
            g2l16(X + (size_t)xr * INDIM + ctc + xcol[i], (char*)Xs + (tid + i * 256) * 16);
        }
        __syncthreads();
#pragma unroll 4
        for (int r = 0; r < 32; r++) {
            float4 u0 = *(const float4*)&UUs[r * 192 + tg * 12];
            float4 u1 = *(const float4*)&UUs[r * 192 + tg * 12 + 4];
            float4 u2 = *(const float4*)&UUs[r * 192 + tg * 12 + 8];
            float2 xv[5];
#pragma unroll
            for (int k = 0; k < 5; k++) xv[k] = *(const float2*)&Xs[r * CTS + tc * 10 + 2 * k];
            float us[12] = {u0.x, u0.y, u0.z, u0.w, u1.x, u1.y, u1.z, u1.w,
                            u2.x, u2.y, u2.z, u2.w};
#pragma unroll
            for (int gg = 0; gg < 12; gg++)
#pragma unroll
                for (int k = 0; k < 5; k++) {
                    acc[gg][k].x = fmaf(us[gg], xv[k].x, acc[gg][k].x);
                    acc[gg][k].y = fmaf(us[gg], xv[k].y, acc[gg][k].y);
                }
        }
    }

    float* pp = partial + (size_t)ks * QSZ;
#pragma unroll
    for (int gg = 0; gg < 12; gg++) {
        int grow = tg * 12 + gg;
        float* dst = pp + (size_t)grow * INDIM + ctc + tc * 10;
#pragma unroll
        for (int k = 0; k < 5; k++) *(float2*)(dst + 2 * k) = acc[gg][k];
    }
}

// reduce split-K partials and fold the per-graph 1/n_g
__global__ void reduce_q(const float* __restrict__ partial, const int* __restrict__ gcnt,
                         float* __restrict__ Q) {
    int o = blockIdx.x * 256 + threadIdx.x;
    if (o >= QSZ) return;
    float a = 0.f;
    for (int ks = 0; ks < KS; ks++) a += partial[(size_t)ks * QSZ + o];
    int g = (o / INDIM) & 63;
    Q[o] = a / (float)max(gcnt[g], 1);
}

// ---------------- R = Q @ W1 with head-algebra epilogue fused --------------------
__global__ __launch_bounds__(256) void gemm_qh(const float* __restrict__ Q,
                                               const float* __restrict__ W1,
                                               const float* __restrict__ sigraw,
                                               const int* __restrict__ gcnt,
                                               const float* __restrict__ b1,
                                               float* __restrict__ G,
                                               float* __restrict__ t2,
                                               float* __restrict__ t3) {
    __shared__ float a_s[32][33];
    int tid = threadIdx.x;
    int c = blockIdx.x * 64 + (tid & 63);
    int grp = tid >> 6;
    int m0 = blockIdx.y * 32;
    float acc[8];
#pragma unroll
    for (int i = 0; i < 8; i++) acc[i] = 0.f;
    for (int k0 = 0; k0 < INDIM; k0 += 32) {
        __syncthreads();
#pragma unroll
        for (int i = 0; i < 4; i++) {
            int idx = tid + i * 256;
            int row = idx >> 5, kk = idx & 31;
            a_s[row][kk] = Q[(size_t)(m0 + row) * INDIM + k0 + kk];
        }
        __syncthreads();
#pragma unroll
        for (int kk = 0; kk < 32; kk++) {
            float w = W1[(size_t)(k0 + kk) * GD + c];
#pragma unroll
            for (int i = 0; i < 8; i++)
                acc[i] = fmaf(a_s[grp * 8 + i][kk], w, acc[i]);
        }
    }
    float bc = b1[c];
#pragma unroll
    for (int i = 0; i < 8; i++) {
        int m = m0 + grp * 8 + i;
        float v = acc[i];
        if (m < 64) {
            G[(size_t)m * CAT + c] = v + bc;
        } else if (m < 128) {
            int g = m - 64;
            float inv = 1.0f / (float)max(gcnt[g], 1);
            t2[(size_t)g * GD + c] = v + sigraw[g] * inv * bc;
        } else {
            int g = m - 128;
            float inv = 1.0f / (float)max(gcnt[g], 1);
            t3[(size_t)g * GD + c] = v + sigraw[64 + g] * inv * bc;
        }
    }
}

// ---------------- dual small GEMM vs W2: G2 = t2@W2 + b2 ; u3 = t3@W2 + sig1*b2 ----
__global__ __launch_bounds__(256) void mm_dual(const float* __restrict__ t2,
                                               const float* __restrict__ t3,
                                               const float* __restrict__ W2,
                                               const float* __restrict__ b2,
                                               const float* __restrict__ sigraw,
                                               const int* __restrict__ gcnt,
                                               float* __restrict__ G,
                                               float* __restrict__ u3) {
    __shared__ float a0[64][33], a1[64][33];
    int tid = threadIdx.x;
    int c = blockIdx.x * 64 + (tid & 63);
    int grp = tid >> 6;
    float acc0[16], acc1[16];
#pragma unroll
    for (int i = 0; i < 16; i++) { acc0[i] = 0.f; acc1[i] = 0.f; }
    for (int k0 = 0; k0 < GD; k0 += 32) {
        __syncthreads();
#pragma unroll
        for (int i = 0; i < 8; i++) {
            int idx = tid + i * 256;
            int m = idx >> 5, kk = idx & 31;
            a0[m][kk] = t2[(size_t)m * GD + k0 + kk];
            a1[m][kk] = t3[(size_t)m * GD + k0 + kk];
        }
        __syncthreads();
#pragma unroll
        for (int kk = 0; kk < 32; kk++) {
            float w = W2[(size_t)(k0 + kk) * GD + c];
#pragma unroll
            for (int i = 0; i < 16; i++) {
                acc0[i] = fmaf(a0[grp * 16 + i][kk], w, acc0[i]);
                acc1[i] = fmaf(a1[grp * 16 + i][kk], w, acc1[i]);
            }
        }
    }
    float bc = b2[c];
#pragma unroll
    for (int i = 0; i < 16; i++) {
        int m = grp * 16 + i;
        G[(size_t)m * CAT + GD + c] = acc0[i] + bc;
        float sg1 = sigraw[m] / (float)max(gcnt[m], 1);
        u3[(size_t)m * GD + c] = acc1[i] + sg1 * bc;
    }
}

// ---------------- small f32 GEMM [64x512] @ [512x512] + bias -------------------
__global__ __launch_bounds__(256) void mm_last(const float* __restrict__ A,
                                               const float* __restrict__ W,
                                               const float* __restrict__ cvec,
                                               float* __restrict__ out, int ostride) {
    __shared__ float a_s[64][33];
    int tid = threadIdx.x;
    int c = blockIdx.x * 64 + (tid & 63);
    int grp = tid >> 6;
    float acc[16];
#pragma unroll
    for (int i = 0; i < 16; i++) acc[i] = 0.f;
    for (int k0 = 0; k0 < GD; k0 += 32) {
        __syncthreads();
#pragma unroll
        for (int i = 0; i < 8; i++) {
            int idx = tid + i * 256;
            int m = idx >> 5, kk = idx & 31;
            a_s[m][kk] = A[(size_t)m * GD + k0 + kk];
        }
        __syncthreads();
#pragma unroll
        for (int kk = 0; kk < 32; kk++) {
            float w = W[(size_t)(k0 + kk) * GD + c];
#pragma unroll
            for (int i = 0; i < 16; i++)
                acc[i] = fmaf(a_s[grp * 16 + i][kk], w, acc[i]);
        }
    }
    float cv = cvec[c];
#pragma unroll
    for (int i = 0; i < 16; i++) {
        int m = grp * 16 + i;
        out[(size_t)m * ostride + c] = acc[i] + cv;
    }
}

// ---------------- small FC: out[64 x NOUT] = act(A[64 x K] @ W + b) ----------------
template <int K, int NOUT, bool RELU>
__global__ __launch_bounds__(256) void fc_kernel(const float* __restrict__ A,
                                                 const float* __restrict__ W,
                                                 const float* __restrict__ bias,
                                                 float* __restrict__ out) {
    __shared__ float a_s[64][33];
    int tid = threadIdx.x;
    int c = blockIdx.x * 64 + (tid & 63);
    int grp = tid >> 6;
    float acc[16];
#pragma unroll
    for (int i = 0; i < 16; i++) acc[i] = 0.f;
    for (int k0 = 0; k0 < K; k0 += 32) {
        __syncthreads();
#pragma unroll
        for (int i = 0; i < 8; i++) {
            int idx = tid + i * 256;
            int m = idx >> 5, kk = idx & 31;
            a_s[m][kk] = A[(size_t)m * K + k0 + kk];
        }
        __syncthreads();
#pragma unroll
        for (int kk = 0; kk < 32; kk++) {
            float w = W[(size_t)(k0 + kk) * NOUT + c];
#pragma unroll
            for (int i = 0; i < 16; i++)
                acc[i] = fmaf(a_s[grp * 16 + i][kk], w, acc[i]);
        }
    }
    float b = bias[c];
#pragma unroll
    for (int i = 0; i < 16; i++) {
        float v = acc[i] + b;
        if (RELU) v = fmaxf(v, 0.f);
        out[(size_t)(grp * 16 + i) * NOUT + c] = v;
    }
}

// ---------------- launch ----------------
static inline size_t al256(size_t x) { return (x + 255) & ~(size_t)255; }

extern "C" void kernel_launch(void* const* d_in, const int* in_sizes, int n_in,
                              void* d_out, int out_size, void* d_ws, size_t ws_size,
                              hipStream_t stream) {
    const float* x   = (const float*)d_in[0];
    const int*   ei  = (const int*)d_in[1];
    const int*   bat = (const int*)d_in[2];
    const float* Wg1 = (const float*)d_in[3];
    const float* bg1 = (const float*)d_in[4];
    const float* Wg2 = (const float*)d_in[5];
    const float* bg2 = (const float*)d_in[6];
    const float* Wg3 = (const float*)d_in[7];
    const float* bg3 = (const float*)d_in[8];
    const float* Wr  = (const float*)d_in[9];
    const float* br  = (const float*)d_in[10];
    const float* Wf  = (const float*)d_in[11];
    const float* bf  = (const float*)d_in[12];
    const float* Wo  = (const float*)d_in[13];
    const float* bo  = (const float*)d_in[14];
    float* out = (float*)d_out;

    char* ws = (char*)d_ws;
    size_t off = 0;
    int*   cnt2    = (int*)(ws + off); off += al256(((size_t)2 * NN + 512) * 4);
    int*   row_ptr = (int*)(ws + off); off += al256((size_t)(NN + 1) * 4);
    int*   fill    = (int*)(ws + off); off += al256((size_t)NN * 4);
    float* dinv    = (float*)(ws + off); off += al256((size_t)NN * 4);
    int*   col     = (int*)(ws + off); off += al256((size_t)EE * 4);
    int*   bsum    = (int*)(ws + off); off += al256(64 * 4);
    float* UU      = (float*)(ws + off); off += al256((size_t)NPAD * 192 * 4);
    float* partial = (float*)(ws + off); off += al256((size_t)KS * QSZ * 4);
    float* Q       = (float*)(ws + off); off += al256((size_t)QSZ * 4);
    float* G       = (float*)(ws + off); off += al256((size_t)NG * CAT * 4);
    float* t2      = (float*)(ws + off); off += al256((size_t)NG * GD * 4);
    float* t3      = (float*)(ws + off); off += al256((size_t)NG * GD * 4);
    float* u3      = (float*)(ws + off); off += al256((size_t)NG * GD * 4);
    float* r0      = (float*)(ws + off); off += al256((size_t)NG * FC0D * 4);
    float* r1      = (float*)(ws + off); off += al256((size_t)NG * FC1D * 4);
    (void)ws_size; (void)n_in; (void)in_sizes; (void)out_size;

    int*   cnt_s  = cnt2;
    int*   cnt_d  = cnt2 + NN;
    int*   gcnt   = cnt2 + 2 * NN;                  // 64 ints
    float* sigraw = (float*)(cnt2 + 2 * NN + 64);   // 128 floats

    const int nscan = (NN + 1023) / 1024;

    // zeros (cnt_s, cnt_d, gcnt, sigraw in one region)
    zero_u32<<<dim3((2 * NN + 512 + 255) / 256), 256, 0, stream>>>((uint32_t*)cnt2, 2 * NN + 512);

    // degree histograms + graph sizes (binary search on sorted batch)
    hist_edges<<<dim3((EE + 255) / 256), 256, 0, stream>>>(ei, cnt_s, cnt_d);
    batch_bounds<<<dim3(1), 64, 0, stream>>>(bat, gcnt);

    // CSR by src
    scan1<<<dim3(nscan), 1024, 0, stream>>>(cnt_s, row_ptr, bsum, NN);
    scan2<<<dim3(1), 64, 0, stream>>>(bsum, nscan);
    scan3b<<<dim3(nscan), 1024, 0, stream>>>(row_ptr, bsum, cnt_d, dinv, fill, NN);
    scatter_src<<<dim3((EE + 255) / 256), 256, 0, stream>>>(ei, fill, col);

    // U propagation into packed UU (pads zero-filled)
    dim3 ugrid((NPAD + 3) / 4);
    uprop_first<<<ugrid, 256, 0, stream>>>(row_ptr, col, dinv, bat, UU);
    uprop_next<<<ugrid, 256, 0, stream>>>(row_ptr, col, dinv, UU, 0, 1);
    uprop_next<<<ugrid, 256, 0, stream>>>(row_ptr, col, dinv, UU, 1, 2);

    // sigma_1/2 raw column sums
    usig_kernel<<<dim3((NN + 511) / 512), 256, 0, stream>>>(UU, sigraw);

    // Q = UU^T X  (X read once; split-K partials -> reduce with 1/n_g)
    contract_kernel<<<dim3(KS * (INDIM / CTS)), 256, 0, stream>>>(x, UU, partial);
    reduce_q<<<dim3((QSZ + 255) / 256), 256, 0, stream>>>(partial, gcnt, Q);

    // R = Q @ W1 with fused head algebra -> G[:, :512], t2, t3
    gemm_qh<<<dim3(GD / 64, 6), 256, 0, stream>>>(Q, Wg1, sigraw, gcnt, bg1, G, t2, t3);
    // G2 = t2@W2 + b2 ; u3 = t3@W2 + sig1*b2   (one pass over W2)
    mm_dual<<<dim3(GD / 64), 256, 0, stream>>>(t2, t3, Wg2, bg2, sigraw, gcnt, G, u3);
    // G3 = u3@W3 + b3
    mm_last<<<dim3(GD / 64), 256, 0, stream>>>(u3, Wg3, bg3, G + 2 * GD, CAT);

    // FC head
    fc_kernel<CAT, FC0D, true><<<dim3(FC0D / 64), 256, 0, stream>>>(G, Wr, br, r0);
    fc_kernel<FC0D, FC1D, true><<<dim3(FC1D / 64), 256, 0, stream>>>(r0, Wf, bf, r1);
    fc_kernel<FC1D, OUTD, false><<<dim3(OUTD / 64), 256, 0, stream>>>(r1, Wo, bo, out);
}

// Round 9
// 1518.571 us; speedup vs baseline: 1.8567x; 1.8567x over previous
//
#include <hip/hip_runtime.h>
#include <stdint.h>

// Problem constants (fixed by the reference)
#define NN 50000
#define EE 800000
#define INDIM 1280
#define GD 512
#define CAT 1536
#define FC0D 1024
#define FC1D 512
#define OUTD 256
#define NG 64

// contraction split-K geometry: grid = KS * 8 ct * 2 gt = 768 = 3 blocks/CU exact
#define KS 48
#define RS 1056                 // KS*RS = 50688 >= NN, RS % 32 == 0
#define NPAD (KS * RS)          // 50688
#define QSZ (192 * INDIM)       // 245760
#define CTS 160                 // contract col-tile (8 tiles over 1280)

__device__ __forceinline__ void g2l16(const void* g, void* l) {
    __builtin_amdgcn_global_load_lds(
        (const __attribute__((address_space(1))) void*)g,
        (__attribute__((address_space(3))) void*)l, 16, 0, 0);
}

// ---------------- utility kernels ----------------
__global__ void zero_u32(uint32_t* p, int n) {
    int i = blockIdx.x * 256 + threadIdx.x;
    if (i < n) p[i] = 0u;
}

// count out-degree (by src) for CSR and in-degree (by dst) for dinv
__global__ void hist_edges(const int* __restrict__ ei, int* __restrict__ cnt_s,
                           int* __restrict__ cnt_d) {
    int e = blockIdx.x * 256 + threadIdx.x;
    if (e < EE) {
        atomicAdd(&cnt_s[ei[e]], 1);
        atomicAdd(&cnt_d[ei[EE + e]], 1);
    }
}

// batch is sorted -> per-graph counts via binary search (no atomics)
__global__ void batch_bounds(const int* __restrict__ bat, int* __restrict__ gcnt) {
    int g = threadIdx.x;   // 0..63
    int lo = 0, hi = NN;
    while (lo < hi) {
        int mid = (lo + hi) >> 1;
        if (bat[mid] < g) lo = mid + 1; else hi = mid;
    }
    int nxt = __shfl_down(lo, 1);
    if (g == 63) nxt = NN;
    gcnt[g] = nxt - lo;
}

__global__ __launch_bounds__(1024) void scan1(const int* __restrict__ cnt,
                                              int* __restrict__ row_ptr,
                                              int* __restrict__ bsum, int n) {
    __shared__ int s[1024];
    int tid = threadIdx.x;
    int i = blockIdx.x * 1024 + tid;
    int v = (i < n) ? cnt[i] : 0;
    s[tid] = v;
    __syncthreads();
    for (int off = 1; off < 1024; off <<= 1) {
        int t = 0;
        if (tid >= off) t = s[tid - off];
        __syncthreads();
        if (tid >= off) s[tid] += t;
        __syncthreads();
    }
    if (i < n) row_ptr[i] = s[tid] - v;
    if (tid == 1023) bsum[blockIdx.x] = s[1023];
}

// wave-parallel exclusive scan of nb (<=64) block sums
__global__ void scan2(int* bsum, int nb) {
    int i = threadIdx.x;
    int v = (i < nb) ? bsum[i] : 0;
    int s = v;
#pragma unroll
    for (int off = 1; off < 64; off <<= 1) {
        int t = __shfl_up(s, off);
        if (i >= off) s += t;
    }
    if (i < nb) bsum[i] = s - v;
}

// finalize row_ptr (by src), emit fill and dinv (from in-degree cnt_d)
__global__ __launch_bounds__(1024) void scan3b(int* __restrict__ row_ptr,
                                               const int* __restrict__ bsum,
                                               const int* __restrict__ cnt_d,
                                               float* __restrict__ dinv,
                                               int* __restrict__ fill, int n) {
    int i = blockIdx.x * 1024 + threadIdx.x;
    if (i < n) {
        int rp = row_ptr[i] + bsum[blockIdx.x];
        row_ptr[i] = rp;
        fill[i] = rp;
        dinv[i] = rsqrtf((float)cnt_d[i] + 1.0f);
    }
    if (i == 0) row_ptr[n] = EE;
}

// CSR by src: col[] holds dst
__global__ void scatter_src(const int* __restrict__ ei, int* __restrict__ fill,
                            int* __restrict__ col) {
    int e = blockIdx.x * 256 + threadIdx.x;
    if (e < EE) {
        int s = ei[e];
        int d = ei[EE + e];
        int pos = atomicAdd(&fill[s], 1);
        col[pos] = d;
    }
}

// ---------------- U propagation into packed UU[NPAD][192] ----------------
// (A_hat^T v)[i] = di^2 v[i] + di * sum_{edges (i->j)} dinv[j] * v[j]
// section 0 = U1, 1 = U2, 2 = U3. Pad rows written zero.
__global__ __launch_bounds__(256) void uprop_first(const int* __restrict__ rp,
                                                   const int* __restrict__ col,
                                                   const float* __restrict__ dinv,
                                                   const int* __restrict__ bat,
                                                   float* __restrict__ UU) {
    int wid = threadIdx.x >> 6, lane = threadIdx.x & 63;
    int i = blockIdx.x * 4 + wid;
    if (i >= NPAD) return;
    if (i >= NN) { UU[(size_t)i * 192 + lane] = 0.f; return; }
    float di = dinv[i];
    float acc = (bat[i] == lane) ? di * di : 0.f;
    int s = rp[i], e = rp[i + 1];
    for (int t = s; t < e; t++) {
        int d = col[t];
        float w = di * dinv[d];
        acc += (bat[d] == lane) ? w : 0.f;
    }
    UU[(size_t)i * 192 + lane] = acc;
}

__global__ __launch_bounds__(256) void uprop_next(const int* __restrict__ rp,
                                                  const int* __restrict__ col,
                                                  const float* __restrict__ dinv,
                                                  float* __restrict__ UU,
                                                  int secIn, int secOut) {
    int wid = threadIdx.x >> 6, lane = threadIdx.x & 63;
    int i = blockIdx.x * 4 + wid;
    if (i >= NPAD) return;
    if (i >= NN) { UU[(size_t)i * 192 + secOut * 64 + lane] = 0.f; return; }
    const float* Uin = UU + secIn * 64;
    float di = dinv[i];
    float acc = di * di * Uin[(size_t)i * 192 + lane];
    int s = rp[i], e = rp[i + 1];
    int t = s;
    for (; t + 3 < e; t += 4) {
        int d0 = col[t], d1 = col[t + 1], d2 = col[t + 2], d3 = col[t + 3];
        float w0 = di * dinv[d0], w1 = di * dinv[d1];
        float w2 = di * dinv[d2], w3 = di * dinv[d3];
        float u0 = Uin[(size_t)d0 * 192 + lane];
        float u1 = Uin[(size_t)d1 * 192 + lane];
        float u2 = Uin[(size_t)d2 * 192 + lane];
        float u3 = Uin[(size_t)d3 * 192 + lane];
        acc = fmaf(u0, w0, acc);
        acc = fmaf(u1, w1, acc);
        acc = fmaf(u2, w2, acc);
        acc = fmaf(u3, w3, acc);
    }
    for (; t < e; t++) {
        int d0 = col[t];
        acc = fmaf(Uin[(size_t)d0 * 192 + lane], di * dinv[d0], acc);
    }
    UU[(size_t)i * 192 + secOut * 64 + lane] = acc;
}

// column sums of UU sec0 (U1) and sec1 (U2) -> sigraw[0..63], sigraw[64..127]
__global__ __launch_bounds__(256) void usig_kernel(const float* __restrict__ UU,
                                                   float* __restrict__ sigraw) {
    int g = threadIdx.x & 63, rs = threadIdx.x >> 6;
    int r0 = blockIdx.x * 512;
    int rend = min(r0 + 512, NN);
    float a1 = 0.f, a2 = 0.f;
    for (int r = r0 + rs; r < rend; r += 4) {
        size_t o = (size_t)r * 192 + g;
        a1 += UU[o];
        a2 += UU[o + 64];
    }
    __shared__ float sh[2][256];
    sh[0][threadIdx.x] = a1;
    sh[1][threadIdx.x] = a2;
    __syncthreads();
    if (rs == 0) {
        a1 = sh[0][g] + sh[0][64 + g] + sh[0][128 + g] + sh[0][192 + g];
        a2 = sh[1][g] + sh[1][64 + g] + sh[1][128 + g] + sh[1][192 + g];
        atomicAdd(&sigraw[g], a1);
        atomicAdd(&sigraw[64 + g], a2);
    }
}

// ---------------- contraction: Q = UU^T X  (f32, split-K partials) ----------
// 1-D grid 768 blocks (3/CU exact), XCD-chunked swizzle.
// Block: 96 g-rows (gt half) x 160 cols. Thread: 6 g x 10 c = 60 acc (no spill).
__global__ __launch_bounds__(256, 3) void contract_kernel(
    const float* __restrict__ X, const float* __restrict__ UU,
    float* __restrict__ partial) {
    __shared__ __align__(16) float UUs[32 * 96];    // 12 KB
    __shared__ __align__(16) float Xs[32 * CTS];    // 20 KB
    // bijective XCD-chunk swizzle: 768 = 8 XCD * 96
    const int sbid = (blockIdx.x & 7) * 96 + (blockIdx.x >> 3);
    const int ks = sbid >> 4;        // 0..47
    const int rem = sbid & 15;
    const int ct = rem >> 1;         // 0..7
    const int gt = rem & 1;          // 0..1  (g-half: rows gt*96..gt*96+95 of UU)
    const int tid = threadIdx.x;
    const int tg = tid >> 4;         // 0..15 -> g-rows tg*6..+5 within the half
    const int tc = tid & 15;         // 0..15 -> cols tc*10..+9
    const int r0 = ks * RS;
    const int ctc = ct * CTS;

    float2 acc[6][5];
#pragma unroll
    for (int gg = 0; gg < 6; gg++)
#pragma unroll
        for (int k = 0; k < 5; k++) acc[gg][k] = make_float2(0.f, 0.f);

    // staging geometry (per thread, loop-invariant)
    int urow[3], ucol[3], xrow[5], xcol[5];
#pragma unroll
    for (int i = 0; i < 3; i++) {
        int p = tid + i * 256;              // 0..767, 24 segs per 96-f row
        urow[i] = p / 24;
        ucol[i] = (p % 24) * 4;
    }
#pragma unroll
    for (int i = 0; i < 5; i++) {
        int p = tid + i * 256;              // 0..1279, 40 segs per 160-f row
        xrow[i] = p / 40;
        xcol[i] = (p % 40) * 4;
    }

    for (int ch = 0; ch < RS / 32; ch++) {
        int rb = r0 + ch * 32;
        __syncthreads();
#pragma unroll
        for (int i = 0; i < 3; i++)
            g2l16(UU + (size_t)(rb + urow[i]) * 192 + gt * 96 + ucol[i],
                  (char*)UUs + (tid + i * 256) * 16);
#pragma unroll
        for (int i = 0; i < 5; i++) {
            int xr = rb + xrow[i];
            if (xr >= NN) xr = NN - 1;      // pad rows: UU is zero there
            g2l16(X + (size_t)xr * INDIM + ctc + xcol[i], (char*)Xs + (tid + i * 256) * 16);
        }
        __syncthreads();
#pragma unroll 4
        for (int r = 0; r < 32; r++) {
            float2 ua = *(const float2*)&UUs[r * 96 + tg * 6];
            float2 ub = *(const float2*)&UUs[r * 96 + tg * 6 + 2];
            float2 uc = *(const float2*)&UUs[r * 96 + tg * 6 + 4];
            float2 xv[5];
#pragma unroll
            for (int k = 0; k < 5; k++) xv[k] = *(const float2*)&Xs[r * CTS + tc * 10 + 2 * k];
            float us[6] = {ua.x, ua.y, ub.x, ub.y, uc.x, uc.y};
#pragma unroll
            for (int gg = 0; gg < 6; gg++)
#pragma unroll
                for (int k = 0; k < 5; k++) {
                    acc[gg][k].x = fmaf(us[gg], xv[k].x, acc[gg][k].x);
                    acc[gg][k].y = fmaf(us[gg], xv[k].y, acc[gg][k].y);
                }
        }
    }

    float* pp = partial + (size_t)ks * QSZ;
#pragma unroll
    for (int gg = 0; gg < 6; gg++) {
        int grow = gt * 96 + tg * 6 + gg;
        float* dst = pp + (size_t)grow * INDIM + ctc + tc * 10;
#pragma unroll
        for (int k = 0; k < 5; k++) *(float2*)(dst + 2 * k) = acc[gg][k];
    }
}

// reduce split-K partials and fold the per-graph 1/n_g
__global__ void reduce_q(const float* __restrict__ partial, const int* __restrict__ gcnt,
                         float* __restrict__ Q) {
    int o = blockIdx.x * 256 + threadIdx.x;
    if (o >= QSZ) return;
    float a = 0.f;
    for (int ks = 0; ks < KS; ks++) a += partial[(size_t)ks * QSZ + o];
    int g = (o / INDIM) & 63;
    Q[o] = a / (float)max(gcnt[g], 1);
}

// ---------------- R = Q @ W1 with head-algebra epilogue fused --------------------
__global__ __launch_bounds__(256) void gemm_qh(const float* __restrict__ Q,
                                               const float* __restrict__ W1,
                                               const float* __restrict__ sigraw,
                                               const int* __restrict__ gcnt,
                                               const float* __restrict__ b1,
                                               float* __restrict__ G,
                                               float* __restrict__ t2,
                                               float* __restrict__ t3) {
    __shared__ float a_s[32][33];
    int tid = threadIdx.x;
    int c = blockIdx.x * 64 + (tid & 63);
    int grp = tid >> 6;
    int m0 = blockIdx.y * 32;
    float acc[8];
#pragma unroll
    for (int i = 0; i < 8; i++) acc[i] = 0.f;
    for (int k0 = 0; k0 < INDIM; k0 += 32) {
        __syncthreads();
#pragma unroll
        for (int i = 0; i < 4; i++) {
            int idx = tid + i * 256;
            int row = idx >> 5, kk = idx & 31;
            a_s[row][kk] = Q[(size_t)(m0 + row) * INDIM + k0 + kk];
        }
        __syncthreads();
#pragma unroll
        for (int kk = 0; kk < 32; kk++) {
            float w = W1[(size_t)(k0 + kk) * GD + c];
#pragma unroll
            for (int i = 0; i < 8; i++)
                acc[i] = fmaf(a_s[grp * 8 + i][kk], w, acc[i]);
        }
    }
    float bc = b1[c];
#pragma unroll
    for (int i = 0; i < 8; i++) {
        int m = m0 + grp * 8 + i;
        float v = acc[i];
        if (m < 64) {
            G[(size_t)m * CAT + c] = v + bc;
        } else if (m < 128) {
            int g = m - 64;
            float inv = 1.0f / (float)max(gcnt[g], 1);
            t2[(size_t)g * GD + c] = v + sigraw[g] * inv * bc;
        } else {
            int g = m - 128;
            float inv = 1.0f / (float)max(gcnt[g], 1);
            t3[(size_t)g * GD + c] = v + sigraw[64 + g] * inv * bc;
        }
    }
}

// ---------------- dual small GEMM vs W2: G2 = t2@W2 + b2 ; u3 = t3@W2 + sig1*b2 ----
__global__ __launch_bounds__(256) void mm_dual(const float* __restrict__ t2,
                                               const float* __restrict__ t3,
                                               const float* __restrict__ W2,
                                               const float* __restrict__ b2,
                                               const float* __restrict__ sigraw,
                                               const int* __restrict__ gcnt,
                                               float* __restrict__ G,
                                               float* __restrict__ u3) {
    __shared__ float a0[64][33], a1[64][33];
    int tid = threadIdx.x;
    int c = blockIdx.x * 64 + (tid & 63);
    int grp = tid >> 6;
    float acc0[16], acc1[16];
#pragma unroll
    for (int i = 0; i < 16; i++) { acc0[i] = 0.f; acc1[i] = 0.f; }
    for (int k0 = 0; k0 < GD; k0 += 32) {
        __syncthreads();
#pragma unroll
        for (int i = 0; i < 8; i++) {
            int idx = tid + i * 256;
            int m = idx >> 5, kk = idx & 31;
            a0[m][kk] = t2[(size_t)m * GD + k0 + kk];
            a1[m][kk] = t3[(size_t)m * GD + k0 + kk];
        }
        __syncthreads();
#pragma unroll
        for (int kk = 0; kk < 32; kk++) {
            float w = W2[(size_t)(k0 + kk) * GD + c];
#pragma unroll
            for (int i = 0; i < 16; i++) {
                acc0[i] = fmaf(a0[grp * 16 + i][kk], w, acc0[i]);
                acc1[i] = fmaf(a1[grp * 16 + i][kk], w, acc1[i]);
            }
        }
    }
    float bc = b2[c];
#pragma unroll
    for (int i = 0; i < 16; i++) {
        int m = grp * 16 + i;
        G[(size_t)m * CAT + GD + c] = acc0[i] + bc;
        float sg1 = sigraw[m] / (float)max(gcnt[m], 1);
        u3[(size_t)m * GD + c] = acc1[i] + sg1 * bc;
    }
}

// ---------------- small f32 GEMM [64x512] @ [512x512] + bias -------------------
__global__ __launch_bounds__(256) void mm_last(const float* __restrict__ A,
                                               const float* __restrict__ W,
                                               const float* __restrict__ cvec,
                                               float* __restrict__ out, int ostride) {
    __shared__ float a_s[64][33];
    int tid = threadIdx.x;
    int c = blockIdx.x * 64 + (tid & 63);
    int grp = tid >> 6;
    float acc[16];
#pragma unroll
    for (int i = 0; i < 16; i++) acc[i] = 0.f;
    for (int k0 = 0; k0 < GD; k0 += 32) {
        __syncthreads();
#pragma unroll
        for (int i = 0; i < 8; i++) {
            int idx = tid + i * 256;
            int m = idx >> 5, kk = idx & 31;
            a_s[m][kk] = A[(size_t)m * GD + k0 + kk];
        }
        __syncthreads();
#pragma unroll
        for (int kk = 0; kk < 32; kk++) {
            float w = W[(size_t)(k0 + kk) * GD + c];
#pragma unroll
            for (int i = 0; i < 16; i++)
                acc[i] = fmaf(a_s[grp * 16 + i][kk], w, acc[i]);
        }
    }
    float cv = cvec[c];
#pragma unroll
    for (int i = 0; i < 16; i++) {
        int m = grp * 16 + i;
        out[(size_t)m * ostride + c] = acc[i] + cv;
    }
}

// ---------------- small FC: out[64 x NOUT] = act(A[64 x K] @ W + b) ----------------
template <int K, int NOUT, bool RELU>
__global__ __launch_bounds__(256) void fc_kernel(const float* __restrict__ A,
                                                 const float* __restrict__ W,
                                                 const float* __restrict__ bias,
                                                 float* __restrict__ out) {
    __shared__ float a_s[64][33];
    int tid = threadIdx.x;
    int c = blockIdx.x * 64 + (tid & 63);
    int grp = tid >> 6;
    float acc[16];
#pragma unroll
    for (int i = 0; i < 16; i++) acc[i] = 0.f;
    for (int k0 = 0; k0 < K; k0 += 32) {
        __syncthreads();
#pragma unroll
        for (int i = 0; i < 8; i++) {
            int idx = tid + i * 256;
            int m = idx >> 5, kk = idx & 31;
            a_s[m][kk] = A[(size_t)m * K + k0 + kk];
        }
        __syncthreads();
#pragma unroll
        for (int kk = 0; kk < 32; kk++) {
            float w = W[(size_t)(k0 + kk) * NOUT + c];
#pragma unroll
            for (int i = 0; i < 16; i++)
                acc[i] = fmaf(a_s[grp * 16 + i][kk], w, acc[i]);
        }
    }
    float b = bias[c];
#pragma unroll
    for (int i = 0; i < 16; i++) {
        float v = acc[i] + b;
        if (RELU) v = fmaxf(v, 0.f);
        out[(size_t)(grp * 16 + i) * NOUT + c] = v;
    }
}

// ---------------- launch ----------------
static inline size_t al256(size_t x) { return (x + 255) & ~(size_t)255; }

extern "C" void kernel_launch(void* const* d_in, const int* in_sizes, int n_in,
                              void* d_out, int out_size, void* d_ws, size_t ws_size,
                              hipStream_t stream) {
    const float* x   = (const float*)d_in[0];
    const int*   ei  = (const int*)d_in[1];
    const int*   bat = (const int*)d_in[2];
    const float* Wg1 = (const float*)d_in[3];
    const float* bg1 = (const float*)d_in[4];
    const float* Wg2 = (const float*)d_in[5];
    const float* bg2 = (const float*)d_in[6];
    const float* Wg3 = (const float*)d_in[7];
    const float* bg3 = (const float*)d_in[8];
    const float* Wr  = (const float*)d_in[9];
    const float* br  = (const float*)d_in[10];
    const float* Wf  = (const float*)d_in[11];
    const float* bf  = (const float*)d_in[12];
    const float* Wo  = (const float*)d_in[13];
    const float* bo  = (const float*)d_in[14];
    float* out = (float*)d_out;

    char* ws = (char*)d_ws;
    size_t off = 0;
    int*   cnt2    = (int*)(ws + off); off += al256(((size_t)2 * NN + 512) * 4);
    int*   row_ptr = (int*)(ws + off); off += al256((size_t)(NN + 1) * 4);
    int*   fill    = (int*)(ws + off); off += al256((size_t)NN * 4);
    float* dinv    = (float*)(ws + off); off += al256((size_t)NN * 4);
    int*   col     = (int*)(ws + off); off += al256((size_t)EE * 4);
    int*   bsum    = (int*)(ws + off); off += al256(64 * 4);
    float* UU      = (float*)(ws + off); off += al256((size_t)NPAD * 192 * 4);
    float* partial = (float*)(ws + off); off += al256((size_t)KS * QSZ * 4);
    float* Q       = (float*)(ws + off); off += al256((size_t)QSZ * 4);
    float* G       = (float*)(ws + off); off += al256((size_t)NG * CAT * 4);
    float* t2      = (float*)(ws + off); off += al256((size_t)NG * GD * 4);
    float* t3      = (float*)(ws + off); off += al256((size_t)NG * GD * 4);
    float* u3      = (float*)(ws + off); off += al256((size_t)NG * GD * 4);
    float* r0      = (float*)(ws + off); off += al256((size_t)NG * FC0D * 4);
    float* r1      = (float*)(ws + off); off += al256((size_t)NG * FC1D * 4);
    (void)ws_size; (void)n_in; (void)in_sizes; (void)out_size;

    int*   cnt_s  = cnt2;
    int*   cnt_d  = cnt2 + NN;
    int*   gcnt   = cnt2 + 2 * NN;                  // 64 ints
    float* sigraw = (float*)(cnt2 + 2 * NN + 64);   // 128 floats

    const int nscan = (NN + 1023) / 1024;

    // zeros (cnt_s, cnt_d, gcnt, sigraw in one region)
    zero_u32<<<dim3((2 * NN + 512 + 255) / 256), 256, 0, stream>>>((uint32_t*)cnt2, 2 * NN + 512);

    // degree histograms + graph sizes (binary search on sorted batch)
    hist_edges<<<dim3((EE + 255) / 256), 256, 0, stream>>>(ei, cnt_s, cnt_d);
    batch_bounds<<<dim3(1), 64, 0, stream>>>(bat, gcnt);

    // CSR by src
    scan1<<<dim3(nscan), 1024, 0, stream>>>(cnt_s, row_ptr, bsum, NN);
    scan2<<<dim3(1), 64, 0, stream>>>(bsum, nscan);
    scan3b<<<dim3(nscan), 1024, 0, stream>>>(row_ptr, bsum, cnt_d, dinv, fill, NN);
    scatter_src<<<dim3((EE + 255) / 256), 256, 0, stream>>>(ei, fill, col);

    // U propagation into packed UU (pads zero-filled)
    dim3 ugrid((NPAD + 3) / 4);
    uprop_first<<<ugrid, 256, 0, stream>>>(row_ptr, col, dinv, bat, UU);
    uprop_next<<<ugrid, 256, 0, stream>>>(row_ptr, col, dinv, UU, 0, 1);
    uprop_next<<<ugrid, 256, 0, stream>>>(row_ptr, col, dinv, UU, 1, 2);

    // sigma_1/2 raw column sums
    usig_kernel<<<dim3((NN + 511) / 512), 256, 0, stream>>>(UU, sigraw);

    // Q = UU^T X  (X read once; split-K partials -> reduce with 1/n_g)
    contract_kernel<<<dim3(768), 256, 0, stream>>>(x, UU, partial);
    reduce_q<<<dim3((QSZ + 255) / 256), 256, 0, stream>>>(partial, gcnt, Q);

    // R = Q @ W1 with fused head algebra -> G[:, :512], t2, t3
    gemm_qh<<<dim3(GD / 64, 6), 256, 0, stream>>>(Q, Wg1, sigraw, gcnt, bg1, G, t2, t3);
    // G2 = t2@W2 + b2 ; u3 = t3@W2 + sig1*b2   (one pass over W2)
    mm_dual<<<dim3(GD / 64), 256, 0, stream>>>(t2, t3, Wg2, bg2, sigraw, gcnt, G, u3);
    // G3 = u3@W3 + b3
    mm_last<<<dim3(GD / 64), 256, 0, stream>>>(u3, Wg3, bg3, G + 2 * GD, CAT);

    // FC head
    fc_kernel<CAT, FC0D, true><<<dim3(FC0D / 64), 256, 0, stream>>>(G, Wr, br, r0);
    fc_kernel<FC0D, FC1D, true><<<dim3(FC1D / 64), 256, 0, stream>>>(r0, Wf, bf, r1);
    fc_kernel<FC1D, OUTD, false><<<dim3(OUTD / 64), 256, 0, stream>>>(r1, Wo, bo, out);
}

// Round 10
// 1472.112 us; speedup vs baseline: 1.9153x; 1.0316x over previous
//
#include <hip/hip_runtime.h>
#include <stdint.h>

// Problem constants (fixed by the reference)
#define NN 50000
#define EE 800000
#define INDIM 1280
#define GD 512
#define CAT 1536
#define FC0D 1024
#define FC1D 512
#define OUTD 256
#define NG 64

// contraction split-K geometry: grid = KS * 8 ct * 2 gt = 768 = 3 blocks/CU exact
#define KS 48
#define RS 1056                 // KS*RS = 50688 >= NN, RS % 32 == 0
#define NPAD (KS * RS)          // 50688
#define QSZ (192 * INDIM)       // 245760
#define CTS 160                 // contract col-tile (8 tiles over 1280)

__device__ __forceinline__ void g2l16(const void* g, void* l) {
    __builtin_amdgcn_global_load_lds(
        (const __attribute__((address_space(1))) void*)g,
        (__attribute__((address_space(3))) void*)l, 16, 0, 0);
}

// ---------------- utility kernels ----------------
__global__ void zero_u32(uint32_t* p, int n) {
    int i = blockIdx.x * 256 + threadIdx.x;
    if (i < n) p[i] = 0u;
}

// count out-degree (by src) for CSR and in-degree (by dst) for dinv
__global__ void hist_edges(const int* __restrict__ ei, int* __restrict__ cnt_s,
                           int* __restrict__ cnt_d) {
    int e = blockIdx.x * 256 + threadIdx.x;
    if (e < EE) {
        atomicAdd(&cnt_s[ei[e]], 1);
        atomicAdd(&cnt_d[ei[EE + e]], 1);
    }
}

// batch is sorted -> per-graph counts via binary search (no atomics)
__global__ void batch_bounds(const int* __restrict__ bat, int* __restrict__ gcnt) {
    int g = threadIdx.x;   // 0..63
    int lo = 0, hi = NN;
    while (lo < hi) {
        int mid = (lo + hi) >> 1;
        if (bat[mid] < g) lo = mid + 1; else hi = mid;
    }
    int nxt = __shfl_down(lo, 1);
    if (g == 63) nxt = NN;
    gcnt[g] = nxt - lo;
}

__global__ __launch_bounds__(1024) void scan1(const int* __restrict__ cnt,
                                              int* __restrict__ row_ptr,
                                              int* __restrict__ bsum, int n) {
    __shared__ int s[1024];
    int tid = threadIdx.x;
    int i = blockIdx.x * 1024 + tid;
    int v = (i < n) ? cnt[i] : 0;
    s[tid] = v;
    __syncthreads();
    for (int off = 1; off < 1024; off <<= 1) {
        int t = 0;
        if (tid >= off) t = s[tid - off];
        __syncthreads();
        if (tid >= off) s[tid] += t;
        __syncthreads();
    }
    if (i < n) row_ptr[i] = s[tid] - v;
    if (tid == 1023) bsum[blockIdx.x] = s[1023];
}

// wave-parallel exclusive scan of nb (<=64) block sums
__global__ void scan2(int* bsum, int nb) {
    int i = threadIdx.x;
    int v = (i < nb) ? bsum[i] : 0;
    int s = v;
#pragma unroll
    for (int off = 1; off < 64; off <<= 1) {
        int t = __shfl_up(s, off);
        if (i >= off) s += t;
    }
    if (i < nb) bsum[i] = s - v;
}

// finalize row_ptr (by src), emit fill and dinv (from in-degree cnt_d)
__global__ __launch_bounds__(1024) void scan3b(int* __restrict__ row_ptr,
                                               const int* __restrict__ bsum,
                                               const int* __restrict__ cnt_d,
                                               float* __restrict__ dinv,
                                               int* __restrict__ fill, int n) {
    int i = blockIdx.x * 1024 + threadIdx.x;
    if (i < n) {
        int rp = row_ptr[i] + bsum[blockIdx.x];
        row_ptr[i] = rp;
        fill[i] = rp;
        dinv[i] = rsqrtf((float)cnt_d[i] + 1.0f);
    }
    if (i == 0) row_ptr[n] = EE;
}

// CSR by src: col[] holds dst
__global__ void scatter_src(const int* __restrict__ ei, int* __restrict__ fill,
                            int* __restrict__ col) {
    int e = blockIdx.x * 256 + threadIdx.x;
    if (e < EE) {
        int s = ei[e];
        int d = ei[EE + e];
        int pos = atomicAdd(&fill[s], 1);
        col[pos] = d;
    }
}

// ---------------- U propagation into packed UU[NPAD][192] ----------------
// (A_hat^T v)[i] = di^2 v[i] + di * sum_{edges (i->j)} dinv[j] * v[j]
// Wave layout: lane = es*16 + f.  es (0..3) = edge slot, f (0..15) = 4-feature group.
// 4 edges gathered concurrently; cross-slot reduce via shfl_xor(16/32).
__global__ __launch_bounds__(256) void uprop_first(const int* __restrict__ rp,
                                                   const int* __restrict__ col,
                                                   const float* __restrict__ dinv,
                                                   const int* __restrict__ bat,
                                                   float* __restrict__ UU) {
    int wid = threadIdx.x >> 6, lane = threadIdx.x & 63;
    int f = lane & 15, es = lane >> 4;
    int i = blockIdx.x * 4 + wid;
    if (i >= NPAD) return;
    float* dst = UU + (size_t)i * 192 + f * 4;
    if (i >= NN) {
        if (es == 0) *(float4*)dst = make_float4(0.f, 0.f, 0.f, 0.f);
        return;
    }
    float di = dinv[i];
    int s = rp[i], e = rp[i + 1];
    float4 a = make_float4(0.f, 0.f, 0.f, 0.f);
    int g0 = f * 4;
    for (int t = s + es; t < e; t += 4) {
        int d = col[t];
        float w = di * dinv[d];
        int b = bat[d];
        a.x += (b == g0 + 0) ? w : 0.f;
        a.y += (b == g0 + 1) ? w : 0.f;
        a.z += (b == g0 + 2) ? w : 0.f;
        a.w += (b == g0 + 3) ? w : 0.f;
    }
    // reduce across edge slots (lane bits 4,5)
#pragma unroll
    for (int m = 16; m <= 32; m <<= 1) {
        a.x += __shfl_xor(a.x, m);
        a.y += __shfl_xor(a.y, m);
        a.z += __shfl_xor(a.z, m);
        a.w += __shfl_xor(a.w, m);
    }
    if (es == 0) {
        int b = bat[i];
        float self = di * di;
        a.x += (b == g0 + 0) ? self : 0.f;
        a.y += (b == g0 + 1) ? self : 0.f;
        a.z += (b == g0 + 2) ? self : 0.f;
        a.w += (b == g0 + 3) ? self : 0.f;
        *(float4*)dst = a;
    }
}

__global__ __launch_bounds__(256) void uprop_next(const int* __restrict__ rp,
                                                  const int* __restrict__ col,
                                                  const float* __restrict__ dinv,
                                                  float* __restrict__ UU,
                                                  int secIn, int secOut) {
    int wid = threadIdx.x >> 6, lane = threadIdx.x & 63;
    int f = lane & 15, es = lane >> 4;
    int i = blockIdx.x * 4 + wid;
    if (i >= NPAD) return;
    float* dst = UU + (size_t)i * 192 + secOut * 64 + f * 4;
    if (i >= NN) {
        if (es == 0) *(float4*)dst = make_float4(0.f, 0.f, 0.f, 0.f);
        return;
    }
    const float* Uin = UU + secIn * 64 + f * 4;
    float di = dinv[i];
    int s = rp[i], e = rp[i + 1];
    float4 a = make_float4(0.f, 0.f, 0.f, 0.f);
    int t = s + es;
    // 2 edges in flight per slot -> 8 per wave
    for (; t + 4 < e; t += 8) {
        int d0 = col[t], d1 = col[t + 4];
        float w0 = di * dinv[d0], w1 = di * dinv[d1];
        float4 u0 = *(const float4*)(Uin + (size_t)d0 * 192);
        float4 u1 = *(const float4*)(Uin + (size_t)d1 * 192);
        a.x = fmaf(w0, u0.x, a.x); a.y = fmaf(w0, u0.y, a.y);
        a.z = fmaf(w0, u0.z, a.z); a.w = fmaf(w0, u0.w, a.w);
        a.x = fmaf(w1, u1.x, a.x); a.y = fmaf(w1, u1.y, a.y);
        a.z = fmaf(w1, u1.z, a.z); a.w = fmaf(w1, u1.w, a.w);
    }
    if (t < e) {
        int d0 = col[t];
        float w0 = di * dinv[d0];
        float4 u0 = *(const float4*)(Uin + (size_t)d0 * 192);
        a.x = fmaf(w0, u0.x, a.x); a.y = fmaf(w0, u0.y, a.y);
        a.z = fmaf(w0, u0.z, a.z); a.w = fmaf(w0, u0.w, a.w);
    }
#pragma unroll
    for (int m = 16; m <= 32; m <<= 1) {
        a.x += __shfl_xor(a.x, m);
        a.y += __shfl_xor(a.y, m);
        a.z += __shfl_xor(a.z, m);
        a.w += __shfl_xor(a.w, m);
    }
    if (es == 0) {
        float self = di * di;
        float4 us = *(const float4*)(Uin + (size_t)i * 192);
        a.x = fmaf(self, us.x, a.x);
        a.y = fmaf(self, us.y, a.y);
        a.z = fmaf(self, us.z, a.z);
        a.w = fmaf(self, us.w, a.w);
        *(float4*)dst = a;
    }
}

// column sums of UU sec0 (U1) and sec1 (U2) -> sigraw[0..63], sigraw[64..127]
__global__ __launch_bounds__(256) void usig_kernel(const float* __restrict__ UU,
                                                   float* __restrict__ sigraw) {
    int g = threadIdx.x & 63, rs = threadIdx.x >> 6;
    int r0 = blockIdx.x * 512;
    int rend = min(r0 + 512, NN);
    float a1 = 0.f, a2 = 0.f;
    for (int r = r0 + rs; r < rend; r += 4) {
        size_t o = (size_t)r * 192 + g;
        a1 += UU[o];
        a2 += UU[o + 64];
    }
    __shared__ float sh[2][256];
    sh[0][threadIdx.x] = a1;
    sh[1][threadIdx.x] = a2;
    __syncthreads();
    if (rs == 0) {
        a1 = sh[0][g] + sh[0][64 + g] + sh[0][128 + g] + sh[0][192 + g];
        a2 = sh[1][g] + sh[1][64 + g] + sh[1][128 + g] + sh[1][192 + g];
        atomicAdd(&sigraw[g], a1);
        atomicAdd(&sigraw[64 + g], a2);
    }
}

// ---------------- contraction: Q = UU^T X  (f32, split-K partials) ----------
// 1-D grid 768 blocks (3/CU exact), XCD-chunked swizzle.
// Block: 96 g-rows (gt half) x 160 cols. Thread: 6 g x 10 c = 60 acc (no spill).
__global__ __launch_bounds__(256, 3) void contract_kernel(
    const float* __restrict__ X, const float* __restrict__ UU,
    float* __restrict__ partial) {
    __shared__ __align__(16) float UUs[32 * 96];    // 12 KB
    __shared__ __align__(16) float Xs[32 * CTS];    // 20 KB
    // bijective XCD-chunk swizzle: 768 = 8 XCD * 96
    const int sbid = (blockIdx.x & 7) * 96 + (blockIdx.x >> 3);
    const int ks = sbid >> 4;        // 0..47
    const int rem = sbid & 15;
    const int ct = rem >> 1;         // 0..7
    const int gt = rem & 1;          // 0..1  (g-half: rows gt*96..gt*96+95 of UU)
    const int tid = threadIdx.x;
    const int tg = tid >> 4;         // 0..15 -> g-rows tg*6..+5 within the half
    const int tc = tid & 15;         // 0..15 -> cols tc*10..+9
    const int r0 = ks * RS;
    const int ctc = ct * CTS;

    float2 acc[6][5];
#pragma unroll
    for (int gg = 0; gg < 6; gg++)
#pragma unroll
        for (int k = 0; k < 5; k++) acc[gg][k] = make_float2(0.f, 0.f);

    // staging geometry (per thread, loop-invariant)
    int urow[3], ucol[3], xrow[5], xcol[5];
#pragma unroll
    for (int i = 0; i < 3; i++) {
        int p = tid + i * 256;              // 0..767, 24 segs per 96-f row
        urow[i] = p / 24;
        ucol[i] = (p % 24) * 4;
    }
#pragma unroll
    for (int i = 0; i < 5; i++) {
        int p = tid + i * 256;              // 0..1279, 40 segs per 160-f row
        xrow[i] = p / 40;
        xcol[i] = (p % 40) * 4;
    }

    for (int ch = 0; ch < RS / 32; ch++) {
        int rb = r0 + ch * 32;
        __syncthreads();
#pragma unroll
        for (int i = 0; i < 3; i++)
            g2l16(UU + (size_t)(rb + urow[i]) * 192 + gt * 96 + ucol[i],
                  (char*)UUs + (tid + i * 256) * 16);
#pragma unroll
        for (int i = 0; i < 5; i++) {
            int xr = rb + xrow[i];
            if (xr >= NN) xr = NN - 1;      // pad rows: UU is zero there
            g2l16(X + (size_t)xr * INDIM + ctc + xcol[i], (char*)Xs + (tid + i * 256) * 16);
        }
        __syncthreads();
#pragma unroll 4
        for (int r = 0; r < 32; r++) {
            float2 ua = *(const float2*)&UUs[r * 96 + tg * 6];
            float2 ub = *(const float2*)&UUs[r * 96 + tg * 6 + 2];
            float2 uc = *(const float2*)&UUs[r * 96 + tg * 6 + 4];
            float2 xv[5];
#pragma unroll
            for (int k = 0; k < 5; k++) xv[k] = *(const float2*)&Xs[r * CTS + tc * 10 + 2 * k];
            float us[6] = {ua.x, ua.y, ub.x, ub.y, uc.x, uc.y};
#pragma unroll
            for (int gg = 0; gg < 6; gg++)
#pragma unroll
                for (int k = 0; k < 5; k++) {
                    acc[gg][k].x = fmaf(us[gg], xv[k].x, acc[gg][k].x);
                    acc[gg][k].y = fmaf(us[gg], xv[k].y, acc[gg][k].y);
                }
        }
    }

    float* pp = partial + (size_t)ks * QSZ;
#pragma unroll
    for (int gg = 0; gg < 6; gg++) {
        int grow = gt * 96 + tg * 6 + gg;
        float* dst = pp + (size_t)grow * INDIM + ctc + tc * 10;
#pragma unroll
        for (int k = 0; k < 5; k++) *(float2*)(dst + 2 * k) = acc[gg][k];
    }
}

// reduce split-K partials and fold the per-graph 1/n_g
__global__ void reduce_q(const float* __restrict__ partial, const int* __restrict__ gcnt,
                         float* __restrict__ Q) {
    int o = blockIdx.x * 256 + threadIdx.x;
    if (o >= QSZ) return;
    float a = 0.f;
    for (int ks = 0; ks < KS; ks++) a += partial[(size_t)ks * QSZ + o];
    int g = (o / INDIM) & 63;
    Q[o] = a / (float)max(gcnt[g], 1);
}

// ---------------- R = Q @ W1 with head-algebra epilogue fused --------------------
__global__ __launch_bounds__(256) void gemm_qh(const float* __restrict__ Q,
                                               const float* __restrict__ W1,
                                               const float* __restrict__ sigraw,
                                               const int* __restrict__ gcnt,
                                               const float* __restrict__ b1,
                                               float* __restrict__ G,
                                               float* __restrict__ t2,
                                               float* __restrict__ t3) {
    __shared__ float a_s[32][33];
    int tid = threadIdx.x;
    int c = blockIdx.x * 64 + (tid & 63);
    int grp = tid >> 6;
    int m0 = blockIdx.y * 32;
    float acc[8];
#pragma unroll
    for (int i = 0; i < 8; i++) acc[i] = 0.f;
    for (int k0 = 0; k0 < INDIM; k0 += 32) {
        __syncthreads();
#pragma unroll
        for (int i = 0; i < 4; i++) {
            int idx = tid + i * 256;
            int row = idx >> 5, kk = idx & 31;
            a_s[row][kk] = Q[(size_t)(m0 + row) * INDIM + k0 + kk];
        }
        __syncthreads();
#pragma unroll
        for (int kk = 0; kk < 32; kk++) {
            float w = W1[(size_t)(k0 + kk) * GD + c];
#pragma unroll
            for (int i = 0; i < 8; i++)
                acc[i] = fmaf(a_s[grp * 8 + i][kk], w, acc[i]);
        }
    }
    float bc = b1[c];
#pragma unroll
    for (int i = 0; i < 8; i++) {
        int m = m0 + grp * 8 + i;
        float v = acc[i];
        if (m < 64) {
            G[(size_t)m * CAT + c] = v + bc;
        } else if (m < 128) {
            int g = m - 64;
            float inv = 1.0f / (float)max(gcnt[g], 1);
            t2[(size_t)g * GD + c] = v + sigraw[g] * inv * bc;
        } else {
            int g = m - 128;
            float inv = 1.0f / (float)max(gcnt[g], 1);
            t3[(size_t)g * GD + c] = v + sigraw[64 + g] * inv * bc;
        }
    }
}

// ---------------- dual small GEMM vs W2: G2 = t2@W2 + b2 ; u3 = t3@W2 + sig1*b2 ----
__global__ __launch_bounds__(256) void mm_dual(const float* __restrict__ t2,
                                               const float* __restrict__ t3,
                                               const float* __restrict__ W2,
                                               const float* __restrict__ b2,
                                               const float* __restrict__ sigraw,
                                               const int* __restrict__ gcnt,
                                               float* __restrict__ G,
                                               float* __restrict__ u3) {
    __shared__ float a0[64][33], a1[64][33];
    int tid = threadIdx.x;
    int c = blockIdx.x * 64 + (tid & 63);
    int grp = tid >> 6;
    float acc0[16], acc1[16];
#pragma unroll
    for (int i = 0; i < 16; i++) { acc0[i] = 0.f; acc1[i] = 0.f; }
    for (int k0 = 0; k0 < GD; k0 += 32) {
        __syncthreads();
#pragma unroll
        for (int i = 0; i < 8; i++) {
            int idx = tid + i * 256;
            int m = idx >> 5, kk = idx & 31;
            a0[m][kk] = t2[(size_t)m * GD + k0 + kk];
            a1[m][kk] = t3[(size_t)m * GD + k0 + kk];
        }
        __syncthreads();
#pragma unroll
        for (int kk = 0; kk < 32; kk++) {
            float w = W2[(size_t)(k0 + kk) * GD + c];
#pragma unroll
            for (int i = 0; i < 16; i++) {
                acc0[i] = fmaf(a0[grp * 16 + i][kk], w, acc0[i]);
                acc1[i] = fmaf(a1[grp * 16 + i][kk], w, acc1[i]);
            }
        }
    }
    float bc = b2[c];
#pragma unroll
    for (int i = 0; i < 16; i++) {
        int m = grp * 16 + i;
        G[(size_t)m * CAT + GD + c] = acc0[i] + bc;
        float sg1 = sigraw[m] / (float)max(gcnt[m], 1);
        u3[(size_t)m * GD + c] = acc1[i] + sg1 * bc;
    }
}

// ---------------- small f32 GEMM [64x512] @ [512x512] + bias -------------------
__global__ __launch_bounds__(256) void mm_last(const float* __restrict__ A,
                                               const float* __restrict__ W,
                                               const float* __restrict__ cvec,
                                               float* __restrict__ out, int ostride) {
    __shared__ float a_s[64][33];
    int tid = threadIdx.x;
    int c = blockIdx.x * 64 + (tid & 63);
    int grp = tid >> 6;
    float acc[16];
#pragma unroll
    for (int i = 0; i < 16; i++) acc[i] = 0.f;
    for (int k0 = 0; k0 < GD; k0 += 32) {
        __syncthreads();
#pragma unroll
        for (int i = 0; i < 8; i++) {
            int idx = tid + i * 256;
            int m = idx >> 5, kk = idx & 31;
            a_s[m][kk] = A[(size_t)m * GD + k0 + kk];
        }
        __syncthreads();
#pragma unroll
        for (int kk = 0; kk < 32; kk++) {
            float w = W[(size_t)(k0 + kk) * GD + c];
#pragma unroll
            for (int i = 0; i < 16; i++)
                acc[i] = fmaf(a_s[grp * 16 + i][kk], w, acc[i]);
        }
    }
    float cv = cvec[c];
#pragma unroll
    for (int i = 0; i < 16; i++) {
        int m = grp * 16 + i;
        out[(size_t)m * ostride + c] = acc[i] + cv;
    }
}

// ---------------- small FC: out[64 x NOUT] = act(A[64 x K] @ W + b) ----------------
template <int K, int NOUT, bool RELU>
__global__ __launch_bounds__(256) void fc_kernel(const float* __restrict__ A,
                                                 const float* __restrict__ W,
                                                 const float* __restrict__ bias,
                                                 float* __restrict__ out) {
    __shared__ float a_s[64][33];
    int tid = threadIdx.x;
    int c = blockIdx.x * 64 + (tid & 63);
    int grp = tid >> 6;
    float acc[16];
#pragma unroll
    for (int i = 0; i < 16; i++) acc[i] = 0.f;
    for (int k0 = 0; k0 < K; k0 += 32) {
        __syncthreads();
#pragma unroll
        for (int i = 0; i < 8; i++) {
            int idx = tid + i * 256;
            int m = idx >> 5, kk = idx & 31;
            a_s[m][kk] = A[(size_t)m * K + k0 + kk];
        }
        __syncthreads();
#pragma unroll
        for (int kk = 0; kk < 32; kk++) {
            float w = W[(size_t)(k0 + kk) * NOUT + c];
#pragma unroll
            for (int i = 0; i < 16; i++)
                acc[i] = fmaf(a_s[grp * 16 + i][kk], w, acc[i]);
        }
    }
    float b = bias[c];
#pragma unroll
    for (int i = 0; i < 16; i++) {
        float v = acc[i] + b;
        if (RELU) v = fmaxf(v, 0.f);
        out[(size_t)(grp * 16 + i) * NOUT + c] = v;
    }
}

// ---------------- launch ----------------
static inline size_t al256(size_t x) { return (x + 255) & ~(size_t)255; }

extern "C" void kernel_launch(void* const* d_in, const int* in_sizes, int n_in,
                              void* d_out, int out_size, void* d_ws, size_t ws_size,
                              hipStream_t stream) {
    const float* x   = (const float*)d_in[0];
    const int*   ei  = (const int*)d_in[1];
    const int*   bat = (const int*)d_in[2];
    const float* Wg1 = (const float*)d_in[3];
    const float* bg1 = (const float*)d_in[4];
    const float* Wg2 = (const float*)d_in[5];
    const float* bg2 = (const float*)d_in[6];
    const float* Wg3 = (const float*)d_in[7];
    const float* bg3 = (const float*)d_in[8];
    const float* Wr  = (const float*)d_in[9];
    const float* br  = (const float*)d_in[10];
    const float* Wf  = (const float*)d_in[11];
    const float* bf  = (const float*)d_in[12];
    const float* Wo  = (const float*)d_in[13];
    const float* bo  = (const float*)d_in[14];
    float* out = (float*)d_out;

    char* ws = (char*)d_ws;
    size_t off = 0;
    int*   cnt2    = (int*)(ws + off); off += al256(((size_t)2 * NN + 512) * 4);
    int*   row_ptr = (int*)(ws + off); off += al256((size_t)(NN + 1) * 4);
    int*   fill    = (int*)(ws + off); off += al256((size_t)NN * 4);
    float* dinv    = (float*)(ws + off); off += al256((size_t)NN * 4);
    int*   col     = (int*)(ws + off); off += al256((size_t)EE * 4);
    int*   bsum    = (int*)(ws + off); off += al256(64 * 4);
    float* UU      = (float*)(ws + off); off += al256((size_t)NPAD * 192 * 4);
    float* partial = (float*)(ws + off); off += al256((size_t)KS * QSZ * 4);
    float* Q       = (float*)(ws + off); off += al256((size_t)QSZ * 4);
    float* G       = (float*)(ws + off); off += al256((size_t)NG * CAT * 4);
    float* t2      = (float*)(ws + off); off += al256((size_t)NG * GD * 4);
    float* t3      = (float*)(ws + off); off += al256((size_t)NG * GD * 4);
    float* u3      = (float*)(ws + off); off += al256((size_t)NG * GD * 4);
    float* r0      = (float*)(ws + off); off += al256((size_t)NG * FC0D * 4);
    float* r1      = (float*)(ws + off); off += al256((size_t)NG * FC1D * 4);
    (void)ws_size; (void)n_in; (void)in_sizes; (void)out_size;

    int*   cnt_s  = cnt2;
    int*   cnt_d  = cnt2 + NN;
    int*   gcnt   = cnt2 + 2 * NN;                  // 64 ints
    float* sigraw = (float*)(cnt2 + 2 * NN + 64);   // 128 floats

    const int nscan = (NN + 1023) / 1024;

    // zeros (cnt_s, cnt_d, gcnt, sigraw in one region)
    zero_u32<<<dim3((2 * NN + 512 + 255) / 256), 256, 0, stream>>>((uint32_t*)cnt2, 2 * NN + 512);

    // degree histograms + graph sizes (binary search on sorted batch)
    hist_edges<<<dim3((EE + 255) / 256), 256, 0, stream>>>(ei, cnt_s, cnt_d);
    batch_bounds<<<dim3(1), 64, 0, stream>>>(bat, gcnt);

    // CSR by src
    scan1<<<dim3(nscan), 1024, 0, stream>>>(cnt_s, row_ptr, bsum, NN);
    scan2<<<dim3(1), 64, 0, stream>>>(bsum, nscan);
    scan3b<<<dim3(nscan), 1024, 0, stream>>>(row_ptr, bsum, cnt_d, dinv, fill, NN);
    scatter_src<<<dim3((EE + 255) / 256), 256, 0, stream>>>(ei, fill, col);

    // U propagation into packed UU (pads zero-filled)
    dim3 ugrid((NPAD + 3) / 4);
    uprop_first<<<ugrid, 256, 0, stream>>>(row_ptr, col, dinv, bat, UU);
    uprop_next<<<ugrid, 256, 0, stream>>>(row_ptr, col, dinv, UU, 0, 1);
    uprop_next<<<ugrid, 256, 0, stream>>>(row_ptr, col, dinv, UU, 1, 2);

    // sigma_1/2 raw column sums
    usig_kernel<<<dim3((NN + 511) / 512), 256, 0, stream>>>(UU, sigraw);

    // Q = UU^T X  (X read once; split-K partials -> reduce with 1/n_g)
    contract_kernel<<<dim3(768), 256, 0, stream>>>(x, UU, partial);
    reduce_q<<<dim3((QSZ + 255) / 256), 256, 0, stream>>>(partial, gcnt, Q);

    // R = Q @ W1 with fused head algebra -> G[:, :512], t2, t3
    gemm_qh<<<dim3(GD / 64, 6), 256, 0, stream>>>(Q, Wg1, sigraw, gcnt, bg1, G, t2, t3);
    // G2 = t2@W2 + b2 ; u3 = t3@W2 + sig1*b2   (one pass over W2)
    mm_dual<<<dim3(GD / 64), 256, 0, stream>>>(t2, t3, Wg2, bg2, sigraw, gcnt, G, u3);
    // G3 = u3@W3 + b3
    mm_last<<<dim3(GD / 64), 256, 0, stream>>>(u3, Wg3, bg3, G + 2 * GD, CAT);

    // FC head
    fc_kernel<CAT, FC0D, true><<<dim3(FC0D / 64), 256, 0, stream>>>(G, Wr, br, r0);
    fc_kernel<FC0D, FC1D, true><<<dim3(FC1D / 64), 256, 0, stream>>>(r0, Wf, bf, r1);
    fc_kernel<FC1D, OUTD, false><<<dim3(OUTD / 64), 256, 0, stream>>>(r1, Wo, bo, out);
}

// Round 11
// 666.661 us; speedup vs baseline: 4.2294x; 2.2082x over previous
//
#include <hip/hip_runtime.h>
#include <stdint.h>

// Problem constants (fixed by the reference)
#define NN 50000
#define EE 800000
#define INDIM 1280
#define GD 512
#define CAT 1536
#define FC0D 1024
#define FC1D 512
#define OUTD 256
#define NG 64

// contraction split-K geometry: grid = KS * 8 ct * 2 gt = 768 = 3 blocks/CU exact
#define KS 48
#define RS 1056                 // KS*RS = 50688 >= NN, RS % 32 == 0
#define NPAD (KS * RS)          // 50688
#define QSZ (192 * INDIM)       // 245760
#define CTS 160                 // contract col-tile (8 tiles over 1280)

__device__ __forceinline__ void g2l16(const void* g, void* l) {
    __builtin_amdgcn_global_load_lds(
        (const __attribute__((address_space(1))) void*)g,
        (__attribute__((address_space(3))) void*)l, 16, 0, 0);
}

// ---------------- utility kernels ----------------
__global__ void zero_u32(uint32_t* p, int n) {
    int i = blockIdx.x * 256 + threadIdx.x;
    if (i < n) p[i] = 0u;
}

// count out-degree (by src) for CSR and in-degree (by dst) for dinv
__global__ void hist_edges(const int* __restrict__ ei, int* __restrict__ cnt_s,
                           int* __restrict__ cnt_d) {
    int e = blockIdx.x * 256 + threadIdx.x;
    if (e < EE) {
        atomicAdd(&cnt_s[ei[e]], 1);
        atomicAdd(&cnt_d[ei[EE + e]], 1);
    }
}

// batch is sorted -> per-graph counts via binary search (no atomics)
__global__ void batch_bounds(const int* __restrict__ bat, int* __restrict__ gcnt) {
    int g = threadIdx.x;   // 0..63
    int lo = 0, hi = NN;
    while (lo < hi) {
        int mid = (lo + hi) >> 1;
        if (bat[mid] < g) lo = mid + 1; else hi = mid;
    }
    int nxt = __shfl_down(lo, 1);
    if (g == 63) nxt = NN;
    gcnt[g] = nxt - lo;
}

__global__ __launch_bounds__(1024) void scan1(const int* __restrict__ cnt,
                                              int* __restrict__ row_ptr,
                                              int* __restrict__ bsum, int n) {
    __shared__ int s[1024];
    int tid = threadIdx.x;
    int i = blockIdx.x * 1024 + tid;
    int v = (i < n) ? cnt[i] : 0;
    s[tid] = v;
    __syncthreads();
    for (int off = 1; off < 1024; off <<= 1) {
        int t = 0;
        if (tid >= off) t = s[tid - off];
        __syncthreads();
        if (tid >= off) s[tid] += t;
        __syncthreads();
    }
    if (i < n) row_ptr[i] = s[tid] - v;
    if (tid == 1023) bsum[blockIdx.x] = s[1023];
}

// wave-parallel exclusive scan of nb (<=64) block sums
__global__ void scan2(int* bsum, int nb) {
    int i = threadIdx.x;
    int v = (i < nb) ? bsum[i] : 0;
    int s = v;
#pragma unroll
    for (int off = 1; off < 64; off <<= 1) {
        int t = __shfl_up(s, off);
        if (i >= off) s += t;
    }
    if (i < nb) bsum[i] = s - v;
}

// finalize row_ptr (by src), emit fill and dinv (from in-degree cnt_d)
__global__ __launch_bounds__(1024) void scan3b(int* __restrict__ row_ptr,
                                               const int* __restrict__ bsum,
                                               const int* __restrict__ cnt_d,
                                               float* __restrict__ dinv,
                                               int* __restrict__ fill, int n) {
    int i = blockIdx.x * 1024 + threadIdx.x;
    if (i < n) {
        int rp = row_ptr[i] + bsum[blockIdx.x];
        row_ptr[i] = rp;
        fill[i] = rp;
        dinv[i] = rsqrtf((float)cnt_d[i] + 1.0f);
    }
    if (i == 0) row_ptr[n] = EE;
}

// CSR by src: col[] holds dst
__global__ void scatter_src(const int* __restrict__ ei, int* __restrict__ fill,
                            int* __restrict__ col) {
    int e = blockIdx.x * 256 + threadIdx.x;
    if (e < EE) {
        int s = ei[e];
        int d = ei[EE + e];
        int pos = atomicAdd(&fill[s], 1);
        col[pos] = d;
    }
}

// ---------------- U propagation into packed UU[NPAD][192] ----------------
// (A_hat^T v)[i] = di^2 v[i] + di * sum_{edges (i->j)} dinv[j] * v[j]
// Wave layout: lane = es*16 + f.  es (0..3) = edge slot, f (0..15) = 4-feature group.
__global__ __launch_bounds__(256) void uprop_first(const int* __restrict__ rp,
                                                   const int* __restrict__ col,
                                                   const float* __restrict__ dinv,
                                                   const int* __restrict__ bat,
                                                   float* __restrict__ UU) {
    int wid = threadIdx.x >> 6, lane = threadIdx.x & 63;
    int f = lane & 15, es = lane >> 4;
    int i = blockIdx.x * 4 + wid;
    if (i >= NPAD) return;
    float* dst = UU + (size_t)i * 192 + f * 4;
    if (i >= NN) {
        if (es == 0) *(float4*)dst = make_float4(0.f, 0.f, 0.f, 0.f);
        return;
    }
    float di = dinv[i];
    int s = rp[i], e = rp[i + 1];
    float4 a = make_float4(0.f, 0.f, 0.f, 0.f);
    int g0 = f * 4;
    for (int t = s + es; t < e; t += 4) {
        int d = col[t];
        float w = di * dinv[d];
        int b = bat[d];
        a.x += (b == g0 + 0) ? w : 0.f;
        a.y += (b == g0 + 1) ? w : 0.f;
        a.z += (b == g0 + 2) ? w : 0.f;
        a.w += (b == g0 + 3) ? w : 0.f;
    }
#pragma unroll
    for (int m = 16; m <= 32; m <<= 1) {
        a.x += __shfl_xor(a.x, m);
        a.y += __shfl_xor(a.y, m);
        a.z += __shfl_xor(a.z, m);
        a.w += __shfl_xor(a.w, m);
    }
    if (es == 0) {
        int b = bat[i];
        float self = di * di;
        a.x += (b == g0 + 0) ? self : 0.f;
        a.y += (b == g0 + 1) ? self : 0.f;
        a.z += (b == g0 + 2) ? self : 0.f;
        a.w += (b == g0 + 3) ? self : 0.f;
        *(float4*)dst = a;
    }
}

__global__ __launch_bounds__(256) void uprop_next(const int* __restrict__ rp,
                                                  const int* __restrict__ col,
                                                  const float* __restrict__ dinv,
                                                  float* __restrict__ UU,
                                                  int secIn, int secOut) {
    int wid = threadIdx.x >> 6, lane = threadIdx.x & 63;
    int f = lane & 15, es = lane >> 4;
    int i = blockIdx.x * 4 + wid;
    if (i >= NPAD) return;
    float* dst = UU + (size_t)i * 192 + secOut * 64 + f * 4;
    if (i >= NN) {
        if (es == 0) *(float4*)dst = make_float4(0.f, 0.f, 0.f, 0.f);
        return;
    }
    const float* Uin = UU + secIn * 64 + f * 4;
    float di = dinv[i];
    int s = rp[i], e = rp[i + 1];
    float4 a = make_float4(0.f, 0.f, 0.f, 0.f);
    int t = s + es;
    for (; t + 4 < e; t += 8) {
        int d0 = col[t], d1 = col[t + 4];
        float w0 = di * dinv[d0], w1 = di * dinv[d1];
        float4 u0 = *(const float4*)(Uin + (size_t)d0 * 192);
        float4 u1 = *(const float4*)(Uin + (size_t)d1 * 192);
        a.x = fmaf(w0, u0.x, a.x); a.y = fmaf(w0, u0.y, a.y);
        a.z = fmaf(w0, u0.z, a.z); a.w = fmaf(w0, u0.w, a.w);
        a.x = fmaf(w1, u1.x, a.x); a.y = fmaf(w1, u1.y, a.y);
        a.z = fmaf(w1, u1.z, a.z); a.w = fmaf(w1, u1.w, a.w);
    }
    if (t < e) {
        int d0 = col[t];
        float w0 = di * dinv[d0];
        float4 u0 = *(const float4*)(Uin + (size_t)d0 * 192);
        a.x = fmaf(w0, u0.x, a.x); a.y = fmaf(w0, u0.y, a.y);
        a.z = fmaf(w0, u0.z, a.z); a.w = fmaf(w0, u0.w, a.w);
    }
#pragma unroll
    for (int m = 16; m <= 32; m <<= 1) {
        a.x += __shfl_xor(a.x, m);
        a.y += __shfl_xor(a.y, m);
        a.z += __shfl_xor(a.z, m);
        a.w += __shfl_xor(a.w, m);
    }
    if (es == 0) {
        float self = di * di;
        float4 us = *(const float4*)(Uin + (size_t)i * 192);
        a.x = fmaf(self, us.x, a.x);
        a.y = fmaf(self, us.y, a.y);
        a.z = fmaf(self, us.z, a.z);
        a.w = fmaf(self, us.w, a.w);
        *(float4*)dst = a;
    }
}

// column sums of UU sec0 (U1) and sec1 (U2) -> sigraw[0..63], sigraw[64..127]
__global__ __launch_bounds__(256) void usig_kernel(const float* __restrict__ UU,
                                                   float* __restrict__ sigraw) {
    int g = threadIdx.x & 63, rs = threadIdx.x >> 6;
    int r0 = blockIdx.x * 512;
    int rend = min(r0 + 512, NN);
    float a1 = 0.f, a2 = 0.f;
    for (int r = r0 + rs; r < rend; r += 4) {
        size_t o = (size_t)r * 192 + g;
        a1 += UU[o];
        a2 += UU[o + 64];
    }
    __shared__ float sh[2][256];
    sh[0][threadIdx.x] = a1;
    sh[1][threadIdx.x] = a2;
    __syncthreads();
    if (rs == 0) {
        a1 = sh[0][g] + sh[0][64 + g] + sh[0][128 + g] + sh[0][192 + g];
        a2 = sh[1][g] + sh[1][64 + g] + sh[1][128 + g] + sh[1][192 + g];
        atomicAdd(&sigraw[g], a1);
        atomicAdd(&sigraw[64 + g], a2);
    }
}

// ---------------- contraction: Q = UU^T X  (f32, split-K partials) ----------
__global__ __launch_bounds__(256, 3) void contract_kernel(
    const float* __restrict__ X, const float* __restrict__ UU,
    float* __restrict__ partial) {
    __shared__ __align__(16) float UUs[32 * 96];    // 12 KB
    __shared__ __align__(16) float Xs[32 * CTS];    // 20 KB
    const int sbid = (blockIdx.x & 7) * 96 + (blockIdx.x >> 3);
    const int ks = sbid >> 4;
    const int rem = sbid & 15;
    const int ct = rem >> 1;
    const int gt = rem & 1;
    const int tid = threadIdx.x;
    const int tg = tid >> 4;
    const int tc = tid & 15;
    const int r0 = ks * RS;
    const int ctc = ct * CTS;

    float2 acc[6][5];
#pragma unroll
    for (int gg = 0; gg < 6; gg++)
#pragma unroll
        for (int k = 0; k < 5; k++) acc[gg][k] = make_float2(0.f, 0.f);

    int urow[3], ucol[3], xrow[5], xcol[5];
#pragma unroll
    for (int i = 0; i < 3; i++) {
        int p = tid + i * 256;
        urow[i] = p / 24;
        ucol[i] = (p % 24) * 4;
    }
#pragma unroll
    for (int i = 0; i < 5; i++) {
        int p = tid + i * 256;
        xrow[i] = p / 40;
        xcol[i] = (p % 40) * 4;
    }

    for (int ch = 0; ch < RS / 32; ch++) {
        int rb = r0 + ch * 32;
        __syncthreads();
#pragma unroll
        for (int i = 0; i < 3; i++)
            g2l16(UU + (size_t)(rb + urow[i]) * 192 + gt * 96 + ucol[i],
                  (char*)UUs + (tid + i * 256) * 16);
#pragma unroll
        for (int i = 0; i < 5; i++) {
            int xr = rb + xrow[i];
            if (xr >= NN) xr = NN - 1;
            g2l16(X + (size_t)xr * INDIM + ctc + xcol[i], (char*)Xs + (tid + i * 256) * 16);
        }
        __syncthreads();
#pragma unroll 4
        for (int r = 0; r < 32; r++) {
            float2 ua = *(const float2*)&UUs[r * 96 + tg * 6];
            float2 ub = *(const float2*)&UUs[r * 96 + tg * 6 + 2];
            float2 uc = *(const float2*)&UUs[r * 96 + tg * 6 + 4];
            float2 xv[5];
#pragma unroll
            for (int k = 0; k < 5; k++) xv[k] = *(const float2*)&Xs[r * CTS + tc * 10 + 2 * k];
            float us[6] = {ua.x, ua.y, ub.x, ub.y, uc.x, uc.y};
#pragma unroll
            for (int gg = 0; gg < 6; gg++)
#pragma unroll
                for (int k = 0; k < 5; k++) {
                    acc[gg][k].x = fmaf(us[gg], xv[k].x, acc[gg][k].x);
                    acc[gg][k].y = fmaf(us[gg], xv[k].y, acc[gg][k].y);
                }
        }
    }

    float* pp = partial + (size_t)ks * QSZ;
#pragma unroll
    for (int gg = 0; gg < 6; gg++) {
        int grow = gt * 96 + tg * 6 + gg;
        float* dst = pp + (size_t)grow * INDIM + ctc + tc * 10;
#pragma unroll
        for (int k = 0; k < 5; k++) *(float2*)(dst + 2 * k) = acc[gg][k];
    }
}

// reduce split-K partials and fold the per-graph 1/n_g
__global__ void reduce_q(const float* __restrict__ partial, const int* __restrict__ gcnt,
                         float* __restrict__ Q) {
    int o = blockIdx.x * 256 + threadIdx.x;
    if (o >= QSZ) return;
    float a = 0.f;
    for (int ks = 0; ks < KS; ks++) a += partial[(size_t)ks * QSZ + o];
    int g = (o / INDIM) & 63;
    Q[o] = a / (float)max(gcnt[g], 1);
}

// ---------------- generic split-K f32 GEMM for the head ----------------
// part[ns][MT][N] += A[MT x K] @ W[K x N] restricted to k-slice ns.
// grid (N/64, MT/32, NS), 256 threads, 32x64 tile, 8 acc/thread.
template <int MT, int K, int N, int NS>
__global__ __launch_bounds__(256) void gemm_sk(const float* __restrict__ A,
                                               const float* __restrict__ W,
                                               float* __restrict__ part) {
    constexpr int KL = K / NS;
    __shared__ float a_s[32][33];
    int tid = threadIdx.x;
    int c = blockIdx.x * 64 + (tid & 63);
    int grp = tid >> 6;
    int m0 = blockIdx.y * 32;
    int k00 = blockIdx.z * KL;
    float acc[8];
#pragma unroll
    for (int i = 0; i < 8; i++) acc[i] = 0.f;
    for (int k0 = k00; k0 < k00 + KL; k0 += 32) {
        __syncthreads();
#pragma unroll
        for (int i = 0; i < 4; i++) {
            int idx = tid + i * 256;
            int row = idx >> 5, kk = idx & 31;
            a_s[row][kk] = A[(size_t)(m0 + row) * K + k0 + kk];
        }
        __syncthreads();
#pragma unroll
        for (int kk = 0; kk < 32; kk++) {
            float w = W[(size_t)(k0 + kk) * N + c];
#pragma unroll
            for (int i = 0; i < 8; i++)
                acc[i] = fmaf(a_s[grp * 8 + i][kk], w, acc[i]);
        }
    }
#pragma unroll
    for (int i = 0; i < 8; i++) {
        int m = m0 + grp * 8 + i;
        part[((size_t)blockIdx.z * MT + m) * N + c] = acc[i];
    }
}

// ---------------- head combine kernels ----------------
// comb_qh: v = sum partQH ; m<64 -> G[:, :512]=v+b1 ; m<128 -> t2=v+sig1*b1 ; else t3=v+sig2*b1
__global__ void comb_qh(const float* __restrict__ p, const float* __restrict__ sigraw,
                        const int* __restrict__ gcnt, const float* __restrict__ b1,
                        float* __restrict__ G, float* __restrict__ t2,
                        float* __restrict__ t3) {
    int o = blockIdx.x * 256 + threadIdx.x;
    if (o >= 192 * GD) return;
    float v = 0.f;
#pragma unroll
    for (int ns = 0; ns < 5; ns++) v += p[(size_t)ns * 192 * GD + o];
    int m = o >> 9, c = o & 511;
    float bc = b1[c];
    if (m < 64) {
        G[(size_t)m * CAT + c] = v + bc;
    } else if (m < 128) {
        int g = m - 64;
        t2[(size_t)g * GD + c] = v + (sigraw[g] / (float)max(gcnt[g], 1)) * bc;
    } else {
        int g = m - 128;
        t3[(size_t)g * GD + c] = v + (sigraw[64 + g] / (float)max(gcnt[g], 1)) * bc;
    }
}

// comb_w2: G[:,512:1024] = sum pA + b2 ; u3 = sum pB + sig1*b2
__global__ void comb_w2(const float* __restrict__ pA, const float* __restrict__ pB,
                        const float* __restrict__ sigraw, const int* __restrict__ gcnt,
                        const float* __restrict__ b2, float* __restrict__ G,
                        float* __restrict__ u3) {
    int o = blockIdx.x * 256 + threadIdx.x;
    if (o >= NG * GD) return;
    float va = 0.f, vb = 0.f;
#pragma unroll
    for (int ns = 0; ns < 4; ns++) {
        va += pA[(size_t)ns * NG * GD + o];
        vb += pB[(size_t)ns * NG * GD + o];
    }
    int m = o >> 9, c = o & 511;
    float bc = b2[c];
    G[(size_t)m * CAT + GD + c] = va + bc;
    u3[o] = vb + (sigraw[m] / (float)max(gcnt[m], 1)) * bc;
}

// comb_w3: G[:,1024:] = sum pC + b3
__global__ void comb_w3(const float* __restrict__ pC, const float* __restrict__ b3,
                        float* __restrict__ G) {
    int o = blockIdx.x * 256 + threadIdx.x;
    if (o >= NG * GD) return;
    float v = 0.f;
#pragma unroll
    for (int ns = 0; ns < 4; ns++) v += pC[(size_t)ns * NG * GD + o];
    int m = o >> 9, c = o & 511;
    G[(size_t)m * CAT + 2 * GD + c] = v + b3[c];
}

// combf: out = (relu)(sum part + bias)
template <int N, int NS, bool RELU>
__global__ void combf(const float* __restrict__ p, const float* __restrict__ bias,
                      float* __restrict__ out) {
    int o = blockIdx.x * 256 + threadIdx.x;
    if (o >= NG * N) return;
    float v = 0.f;
#pragma unroll
    for (int ns = 0; ns < NS; ns++) v += p[(size_t)ns * NG * N + o];
    v += bias[o % N];
    if (RELU) v = fmaxf(v, 0.f);
    out[o] = v;
}

// ---------------- launch ----------------
static inline size_t al256(size_t x) { return (x + 255) & ~(size_t)255; }

extern "C" void kernel_launch(void* const* d_in, const int* in_sizes, int n_in,
                              void* d_out, int out_size, void* d_ws, size_t ws_size,
                              hipStream_t stream) {
    const float* x   = (const float*)d_in[0];
    const int*   ei  = (const int*)d_in[1];
    const int*   bat = (const int*)d_in[2];
    const float* Wg1 = (const float*)d_in[3];
    const float* bg1 = (const float*)d_in[4];
    const float* Wg2 = (const float*)d_in[5];
    const float* bg2 = (const float*)d_in[6];
    const float* Wg3 = (const float*)d_in[7];
    const float* bg3 = (const float*)d_in[8];
    const float* Wr  = (const float*)d_in[9];
    const float* br  = (const float*)d_in[10];
    const float* Wf  = (const float*)d_in[11];
    const float* bf  = (const float*)d_in[12];
    const float* Wo  = (const float*)d_in[13];
    const float* bo  = (const float*)d_in[14];
    float* out = (float*)d_out;

    char* ws = (char*)d_ws;
    size_t off = 0;
    int*   cnt2    = (int*)(ws + off); off += al256(((size_t)2 * NN + 512) * 4);
    int*   row_ptr = (int*)(ws + off); off += al256((size_t)(NN + 1) * 4);
    int*   fill    = (int*)(ws + off); off += al256((size_t)NN * 4);
    float* dinv    = (float*)(ws + off); off += al256((size_t)NN * 4);
    int*   col     = (int*)(ws + off); off += al256((size_t)EE * 4);
    int*   bsum    = (int*)(ws + off); off += al256(64 * 4);
    float* UU      = (float*)(ws + off); off += al256((size_t)NPAD * 192 * 4);
    float* partial = (float*)(ws + off); off += al256((size_t)KS * QSZ * 4);
    float* Q       = (float*)(ws + off); off += al256((size_t)QSZ * 4);
    float* G       = (float*)(ws + off); off += al256((size_t)NG * CAT * 4);
    float* t2      = (float*)(ws + off); off += al256((size_t)NG * GD * 4);
    float* t3      = (float*)(ws + off); off += al256((size_t)NG * GD * 4);
    float* u3      = (float*)(ws + off); off += al256((size_t)NG * GD * 4);
    float* r0      = (float*)(ws + off); off += al256((size_t)NG * FC0D * 4);
    float* r1      = (float*)(ws + off); off += al256((size_t)NG * FC1D * 4);
    float* pQH     = (float*)(ws + off); off += al256((size_t)5 * 192 * GD * 4);
    float* pA      = (float*)(ws + off); off += al256((size_t)4 * NG * GD * 4);
    float* pB      = (float*)(ws + off); off += al256((size_t)4 * NG * GD * 4);
    float* pC      = (float*)(ws + off); off += al256((size_t)4 * NG * GD * 4);
    float* pD      = (float*)(ws + off); off += al256((size_t)6 * NG * FC0D * 4);
    float* pE      = (float*)(ws + off); off += al256((size_t)8 * NG * FC1D * 4);
    float* pF      = (float*)(ws + off); off += al256((size_t)4 * NG * OUTD * 4);
    (void)ws_size; (void)n_in; (void)in_sizes; (void)out_size;

    int*   cnt_s  = cnt2;
    int*   cnt_d  = cnt2 + NN;
    int*   gcnt   = cnt2 + 2 * NN;                  // 64 ints
    float* sigraw = (float*)(cnt2 + 2 * NN + 64);   // 128 floats

    const int nscan = (NN + 1023) / 1024;

    // zeros (cnt_s, cnt_d, gcnt, sigraw in one region)
    zero_u32<<<dim3((2 * NN + 512 + 255) / 256), 256, 0, stream>>>((uint32_t*)cnt2, 2 * NN + 512);

    // degree histograms + graph sizes
    hist_edges<<<dim3((EE + 255) / 256), 256, 0, stream>>>(ei, cnt_s, cnt_d);
    batch_bounds<<<dim3(1), 64, 0, stream>>>(bat, gcnt);

    // CSR by src
    scan1<<<dim3(nscan), 1024, 0, stream>>>(cnt_s, row_ptr, bsum, NN);
    scan2<<<dim3(1), 64, 0, stream>>>(bsum, nscan);
    scan3b<<<dim3(nscan), 1024, 0, stream>>>(row_ptr, bsum, cnt_d, dinv, fill, NN);
    scatter_src<<<dim3((EE + 255) / 256), 256, 0, stream>>>(ei, fill, col);

    // U propagation into packed UU (pads zero-filled)
    dim3 ugrid((NPAD + 3) / 4);
    uprop_first<<<ugrid, 256, 0, stream>>>(row_ptr, col, dinv, bat, UU);
    uprop_next<<<ugrid, 256, 0, stream>>>(row_ptr, col, dinv, UU, 0, 1);
    uprop_next<<<ugrid, 256, 0, stream>>>(row_ptr, col, dinv, UU, 1, 2);

    // sigma_1/2 raw column sums
    usig_kernel<<<dim3((NN + 511) / 512), 256, 0, stream>>>(UU, sigraw);

    // Q = UU^T X
    contract_kernel<<<dim3(768), 256, 0, stream>>>(x, UU, partial);
    reduce_q<<<dim3((QSZ + 255) / 256), 256, 0, stream>>>(partial, gcnt, Q);

    // head: all GEMMs split-K parallel, combines apply bias/sigma/relu algebra
    // R = Q @ W1
    gemm_sk<192, INDIM, GD, 5><<<dim3(GD / 64, 6, 5), 256, 0, stream>>>(Q, Wg1, pQH);
    comb_qh<<<dim3((192 * GD + 255) / 256), 256, 0, stream>>>(pQH, sigraw, gcnt, bg1, G, t2, t3);
    // t2@W2, t3@W2
    gemm_sk<NG, GD, GD, 4><<<dim3(GD / 64, 2, 4), 256, 0, stream>>>(t2, Wg2, pA);
    gemm_sk<NG, GD, GD, 4><<<dim3(GD / 64, 2, 4), 256, 0, stream>>>(t3, Wg2, pB);
    comb_w2<<<dim3((NG * GD + 255) / 256), 256, 0, stream>>>(pA, pB, sigraw, gcnt, bg2, G, u3);
    // u3@W3
    gemm_sk<NG, GD, GD, 4><<<dim3(GD / 64, 2, 4), 256, 0, stream>>>(u3, Wg3, pC);
    comb_w3<<<dim3((NG * GD + 255) / 256), 256, 0, stream>>>(pC, bg3, G);
    // FC head
    gemm_sk<NG, CAT, FC0D, 6><<<dim3(FC0D / 64, 2, 6), 256, 0, stream>>>(G, Wr, pD);
    combf<FC0D, 6, true><<<dim3((NG * FC0D + 255) / 256), 256, 0, stream>>>(pD, br, r0);
    gemm_sk<NG, FC0D, FC1D, 8><<<dim3(FC1D / 64, 2, 8), 256, 0, stream>>>(r0, Wf, pE);
    combf<FC1D, 8, true><<<dim3((NG * FC1D + 255) / 256), 256, 0, stream>>>(pE, bf, r1);
    gemm_sk<NG, FC1D, OUTD, 4><<<dim3(OUTD / 64, 2, 4), 256, 0, stream>>>(r1, Wo, pF);
    combf<OUTD, 4, false><<<dim3((NG * OUTD + 255) / 256), 256, 0, stream>>>(pF, bo, out);
}

// Round 12
// 487.618 us; speedup vs baseline: 5.7823x; 1.3672x over previous
//
#include <hip/hip_runtime.h>
#include <stdint.h>

// Problem constants (fixed by the reference)
#define NN 50000
#define EE 800000
#define INDIM 1280
#define GD 512
#define CAT 1536
#define FC0D 1024
#define FC1D 512
#define OUTD 256
#define NG 64

// contraction (MFMA) split-K geometry: grid = 10 mt * 76 ks = 760 blocks
#define CKS 76
#define CRS 672                 // 76*672 = 51072 >= NN, %32==0
#define NPAD (CKS * CRS)        // 51072
#define QSZ (192 * INDIM)       // 245760 (also = 1280*192)

typedef __attribute__((ext_vector_type(8))) __bf16 bf16x8;
typedef __attribute__((ext_vector_type(4))) float f32x4;

__device__ __forceinline__ void split_bf16(float f, unsigned short& h, unsigned short& l) {
    unsigned int u = __builtin_bit_cast(unsigned int, f);
    h = (unsigned short)(u >> 16);                       // truncated hi
    float hf = __builtin_bit_cast(float, u & 0xffff0000u);
    float lf = f - hf;                                   // exact residual
    unsigned int ul = __builtin_bit_cast(unsigned int, lf);
    ul = ul + 0x7fffu + ((ul >> 16) & 1u);               // RNE lo
    l = (unsigned short)(ul >> 16);
}

__device__ __forceinline__ void g2l16(const void* g, void* l) {
    __builtin_amdgcn_global_load_lds(
        (const __attribute__((address_space(1))) void*)g,
        (__attribute__((address_space(3))) void*)l, 16, 0, 0);
}

// ---------------- utility kernels ----------------
__global__ void zero_u32(uint32_t* p, int n) {
    int i = blockIdx.x * 256 + threadIdx.x;
    if (i < n) p[i] = 0u;
}

__global__ void hist_edges(const int* __restrict__ ei, int* __restrict__ cnt_s,
                           int* __restrict__ cnt_d) {
    int e = blockIdx.x * 256 + threadIdx.x;
    if (e < EE) {
        atomicAdd(&cnt_s[ei[e]], 1);
        atomicAdd(&cnt_d[ei[EE + e]], 1);
    }
}

__global__ void batch_bounds(const int* __restrict__ bat, int* __restrict__ gcnt) {
    int g = threadIdx.x;   // 0..63
    int lo = 0, hi = NN;
    while (lo < hi) {
        int mid = (lo + hi) >> 1;
        if (bat[mid] < g) lo = mid + 1; else hi = mid;
    }
    int nxt = __shfl_down(lo, 1);
    if (g == 63) nxt = NN;
    gcnt[g] = nxt - lo;
}

__global__ __launch_bounds__(1024) void scan1(const int* __restrict__ cnt,
                                              int* __restrict__ row_ptr,
                                              int* __restrict__ bsum, int n) {
    __shared__ int s[1024];
    int tid = threadIdx.x;
    int i = blockIdx.x * 1024 + tid;
    int v = (i < n) ? cnt[i] : 0;
    s[tid] = v;
    __syncthreads();
    for (int off = 1; off < 1024; off <<= 1) {
        int t = 0;
        if (tid >= off) t = s[tid - off];
        __syncthreads();
        if (tid >= off) s[tid] += t;
        __syncthreads();
    }
    if (i < n) row_ptr[i] = s[tid] - v;
    if (tid == 1023) bsum[blockIdx.x] = s[1023];
}

__global__ void scan2(int* bsum, int nb) {
    int i = threadIdx.x;
    int v = (i < nb) ? bsum[i] : 0;
    int s = v;
#pragma unroll
    for (int off = 1; off < 64; off <<= 1) {
        int t = __shfl_up(s, off);
        if (i >= off) s += t;
    }
    if (i < nb) bsum[i] = s - v;
}

__global__ __launch_bounds__(1024) void scan3b(int* __restrict__ row_ptr,
                                               const int* __restrict__ bsum,
                                               const int* __restrict__ cnt_d,
                                               float* __restrict__ dinv,
                                               int* __restrict__ fill, int n) {
    int i = blockIdx.x * 1024 + threadIdx.x;
    if (i < n) {
        int rp = row_ptr[i] + bsum[blockIdx.x];
        row_ptr[i] = rp;
        fill[i] = rp;
        dinv[i] = rsqrtf((float)cnt_d[i] + 1.0f);
    }
    if (i == 0) row_ptr[n] = EE;
}

__global__ void scatter_src(const int* __restrict__ ei, int* __restrict__ fill,
                            int* __restrict__ col) {
    int e = blockIdx.x * 256 + threadIdx.x;
    if (e < EE) {
        int s = ei[e];
        int d = ei[EE + e];
        int pos = atomicAdd(&fill[s], 1);
        col[pos] = d;
    }
}

// ---------------- U propagation into packed UU[NPAD][192] ----------------
__global__ __launch_bounds__(256) void uprop_first(const int* __restrict__ rp,
                                                   const int* __restrict__ col,
                                                   const float* __restrict__ dinv,
                                                   const int* __restrict__ bat,
                                                   float* __restrict__ UU) {
    int wid = threadIdx.x >> 6, lane = threadIdx.x & 63;
    int f = lane & 15, es = lane >> 4;
    int i = blockIdx.x * 4 + wid;
    if (i >= NPAD) return;
    float* dst = UU + (size_t)i * 192 + f * 4;
    if (i >= NN) {
        if (es == 0) *(float4*)dst = make_float4(0.f, 0.f, 0.f, 0.f);
        return;
    }
    float di = dinv[i];
    int s = rp[i], e = rp[i + 1];
    float4 a = make_float4(0.f, 0.f, 0.f, 0.f);
    int g0 = f * 4;
    for (int t = s + es; t < e; t += 4) {
        int d = col[t];
        float w = di * dinv[d];
        int b = bat[d];
        a.x += (b == g0 + 0) ? w : 0.f;
        a.y += (b == g0 + 1) ? w : 0.f;
        a.z += (b == g0 + 2) ? w : 0.f;
        a.w += (b == g0 + 3) ? w : 0.f;
    }
#pragma unroll
    for (int m = 16; m <= 32; m <<= 1) {
        a.x += __shfl_xor(a.x, m);
        a.y += __shfl_xor(a.y, m);
        a.z += __shfl_xor(a.z, m);
        a.w += __shfl_xor(a.w, m);
    }
    if (es == 0) {
        int b = bat[i];
        float self = di * di;
        a.x += (b == g0 + 0) ? self : 0.f;
        a.y += (b == g0 + 1) ? self : 0.f;
        a.z += (b == g0 + 2) ? self : 0.f;
        a.w += (b == g0 + 3) ? self : 0.f;
        *(float4*)dst = a;
    }
}

__global__ __launch_bounds__(256) void uprop_next(const int* __restrict__ rp,
                                                  const int* __restrict__ col,
                                                  const float* __restrict__ dinv,
                                                  float* __restrict__ UU,
                                                  int secIn, int secOut) {
    int wid = threadIdx.x >> 6, lane = threadIdx.x & 63;
    int f = lane & 15, es = lane >> 4;
    int i = blockIdx.x * 4 + wid;
    if (i >= NPAD) return;
    float* dst = UU + (size_t)i * 192 + secOut * 64 + f * 4;
    if (i >= NN) {
        if (es == 0) *(float4*)dst = make_float4(0.f, 0.f, 0.f, 0.f);
        return;
    }
    const float* Uin = UU + secIn * 64 + f * 4;
    float di = dinv[i];
    int s = rp[i], e = rp[i + 1];
    float4 a = make_float4(0.f, 0.f, 0.f, 0.f);
    int t = s + es;
    for (; t + 4 < e; t += 8) {
        int d0 = col[t], d1 = col[t + 4];
        float w0 = di * dinv[d0], w1 = di * dinv[d1];
        float4 u0 = *(const float4*)(Uin + (size_t)d0 * 192);
        float4 u1 = *(const float4*)(Uin + (size_t)d1 * 192);
        a.x = fmaf(w0, u0.x, a.x); a.y = fmaf(w0, u0.y, a.y);
        a.z = fmaf(w0, u0.z, a.z); a.w = fmaf(w0, u0.w, a.w);
        a.x = fmaf(w1, u1.x, a.x); a.y = fmaf(w1, u1.y, a.y);
        a.z = fmaf(w1, u1.z, a.z); a.w = fmaf(w1, u1.w, a.w);
    }
    if (t < e) {
        int d0 = col[t];
        float w0 = di * dinv[d0];
        float4 u0 = *(const float4*)(Uin + (size_t)d0 * 192);
        a.x = fmaf(w0, u0.x, a.x); a.y = fmaf(w0, u0.y, a.y);
        a.z = fmaf(w0, u0.z, a.z); a.w = fmaf(w0, u0.w, a.w);
    }
#pragma unroll
    for (int m = 16; m <= 32; m <<= 1) {
        a.x += __shfl_xor(a.x, m);
        a.y += __shfl_xor(a.y, m);
        a.z += __shfl_xor(a.z, m);
        a.w += __shfl_xor(a.w, m);
    }
    if (es == 0) {
        float self = di * di;
        float4 us = *(const float4*)(Uin + (size_t)i * 192);
        a.x = fmaf(self, us.x, a.x);
        a.y = fmaf(self, us.y, a.y);
        a.z = fmaf(self, us.z, a.z);
        a.w = fmaf(self, us.w, a.w);
        *(float4*)dst = a;
    }
}

// column sums of UU sec0 (U1) and sec1 (U2) -> sigraw[0..63], sigraw[64..127]
__global__ __launch_bounds__(256) void usig_kernel(const float* __restrict__ UU,
                                                   float* __restrict__ sigraw) {
    int g = threadIdx.x & 63, rs = threadIdx.x >> 6;
    int r0 = blockIdx.x * 512;
    int rend = min(r0 + 512, NN);
    float a1 = 0.f, a2 = 0.f;
    for (int r = r0 + rs; r < rend; r += 4) {
        size_t o = (size_t)r * 192 + g;
        a1 += UU[o];
        a2 += UU[o + 64];
    }
    __shared__ float sh[2][256];
    sh[0][threadIdx.x] = a1;
    sh[1][threadIdx.x] = a2;
    __syncthreads();
    if (rs == 0) {
        a1 = sh[0][g] + sh[0][64 + g] + sh[0][128 + g] + sh[0][192 + g];
        a2 = sh[1][g] + sh[1][64 + g] + sh[1][128 + g] + sh[1][192 + g];
        atomicAdd(&sigraw[g], a1);
        atomicAdd(&sigraw[64 + g], a2);
    }
}

// ---------------- UU -> UUT transpose + bf16 hi/lo split ----------------
// UU[NPAD][192] f32 -> UUTH/UUTL[192][NPAD] bf16. Pad rows of UU are zero ->
// pad cols of UUT are exactly zero (kills A-side garbage in the MFMA).
__global__ __launch_bounds__(256) void tsplit_uu(const float* __restrict__ UU,
                                                 unsigned short* __restrict__ TH,
                                                 unsigned short* __restrict__ TL) {
    __shared__ float t[32][33];
    int r0 = blockIdx.x * 32;   // node dim
    int c0 = blockIdx.y * 32;   // g dim (192)
    int r = threadIdx.x >> 3;
    int c4 = (threadIdx.x & 7) * 4;
    float4 v = *(const float4*)(UU + (size_t)(r0 + r) * 192 + c0 + c4);
    t[r][c4 + 0] = v.x;
    t[r][c4 + 1] = v.y;
    t[r][c4 + 2] = v.z;
    t[r][c4 + 3] = v.w;
    __syncthreads();
    ushort4 h4, l4;
    split_bf16(t[c4 + 0][r], h4.x, l4.x);
    split_bf16(t[c4 + 1][r], h4.y, l4.y);
    split_bf16(t[c4 + 2][r], h4.z, l4.z);
    split_bf16(t[c4 + 3][r], h4.w, l4.w);
    *(ushort4*)(TH + (size_t)(c0 + r) * NPAD + r0 + c4) = h4;
    *(ushort4*)(TL + (size_t)(c0 + r) * NPAD + r0 + c4) = l4;
}

// ---------------- MFMA contraction: C[1280 x 192] = X^T (3-term bf16 split) UU ----
// A[m][k] = X[k][m]: staged f32 into LDS (XOR-swizzled), split to bf16 in-reg.
// B[k][n] = UU[k][n]: from UUT[192][NPAD] bf16 hi/lo via global_load_lds.
// Block 128m x 192n, 4 waves (wave 32m x 192n), K-step 32. Grid 760 = 10mt x 76ks.
__global__ __launch_bounds__(256, 3) void contract_mfma(
    const float* __restrict__ X, const unsigned short* __restrict__ UTH,
    const unsigned short* __restrict__ UTL, float* __restrict__ partial) {
    __shared__ __align__(16) float Xs[32 * 128];             // 16 KB
    __shared__ __align__(16) unsigned short Bh[192 * 32];    // 12 KB
    __shared__ __align__(16) unsigned short Bl[192 * 32];    // 12 KB
    // bijective XCD-chunk swizzle (760 = 8*95); ks-major so UUT slice is L2-local
    const int sbid = (blockIdx.x & 7) * 95 + (blockIdx.x >> 3);
    const int ks = sbid / 10, mt = sbid % 10;
    const int tid = threadIdx.x, lane = tid & 63, wid = tid >> 6;
    const int wm = wid * 32;
    const int m0 = mt * 128;
    const int r0 = ks * CRS;
    const int khi = lane >> 4;
    const int ml = lane & 15;

    f32x4 acc[2][12];
#pragma unroll
    for (int mf = 0; mf < 2; mf++)
#pragma unroll
        for (int nf = 0; nf < 12; nf++) acc[mf][nf] = (f32x4)0.0f;

    // staging geometry (loop-invariant)
    // Xs: 1024 16B-segs, 4/thread. dest chunk mc = p&31; source col-chunk swizzled.
    int xsrow[4], xscol[4];
#pragma unroll
    for (int i = 0; i < 4; i++) {
        int p = tid + i * 256;
        int krow = p >> 5;
        xsrow[i] = krow;
        xscol[i] = ((p & 31) ^ ((krow >> 3) << 2)) * 4;
    }

    for (int ch = 0; ch < CRS / 32; ch++) {
        int rb = r0 + ch * 32;
        __syncthreads();
#pragma unroll
        for (int i = 0; i < 4; i++) {
            int xr = rb + xsrow[i];
            if (xr > NN - 1) xr = NN - 1;   // garbage ok: UUT pad cols are zero
            g2l16(X + (size_t)xr * INDIM + m0 + xscol[i], (char*)Xs + (tid + i * 256) * 16);
        }
#pragma unroll
        for (int i = 0; i < 3; i++) {
            int p = tid + i * 256;
            size_t so = (size_t)(p >> 2) * NPAD + rb + (p & 3) * 8;
            g2l16(UTH + so, (char*)Bh + p * 16);
            g2l16(UTL + so, (char*)Bl + p * 16);
        }
        __syncthreads();

        // A-frags: element (k=khi*8+j, m) lives at LDS chunk (m>>2)^(khi<<2)
        bf16x8 ah[2], al[2];
#pragma unroll
        for (int mf = 0; mf < 2; mf++) {
            int mloc = wm + mf * 16 + ml;
            const float* xb = Xs + (size_t)(khi * 8) * 128 +
                              (((mloc >> 2) ^ (khi << 2)) << 2) + (mloc & 3);
            union { bf16x8 v; unsigned short s[8]; } uh, ul;
#pragma unroll
            for (int j = 0; j < 8; j++) {
                unsigned short h, l;
                split_bf16(xb[j * 128], h, l);
                uh.s[j] = h;
                ul.s[j] = l;
            }
            ah[mf] = uh.v;
            al[mf] = ul.v;
        }
#pragma unroll
        for (int nf = 0; nf < 12; nf++) {
            int nrow = nf * 16 + ml;
            bf16x8 bh = *(const bf16x8*)(Bh + nrow * 32 + khi * 8);
            bf16x8 bl = *(const bf16x8*)(Bl + nrow * 32 + khi * 8);
#pragma unroll
            for (int mf = 0; mf < 2; mf++) {
                acc[mf][nf] = __builtin_amdgcn_mfma_f32_16x16x32_bf16(ah[mf], bh, acc[mf][nf], 0, 0, 0);
                acc[mf][nf] = __builtin_amdgcn_mfma_f32_16x16x32_bf16(ah[mf], bl, acc[mf][nf], 0, 0, 0);
                acc[mf][nf] = __builtin_amdgcn_mfma_f32_16x16x32_bf16(al[mf], bh, acc[mf][nf], 0, 0, 0);
            }
        }
    }

    // epilogue: C/D layout col=lane&15 (n), row=(lane>>4)*4+r (m)
    float* pp = partial + (size_t)ks * QSZ;
#pragma unroll
    for (int mf = 0; mf < 2; mf++) {
        int mg = m0 + wm + mf * 16 + khi * 4;
#pragma unroll
        for (int nf = 0; nf < 12; nf++) {
            int n = nf * 16 + ml;
#pragma unroll
            for (int r = 0; r < 4; r++)
                pp[(size_t)(mg + r) * 192 + n] = acc[mf][nf][r];
        }
    }
}

// reduce split-K partials [CKS][1280][192] -> Q[192][1280], fold 1/n_g
__global__ void reduce_qt(const float* __restrict__ partial, const int* __restrict__ gcnt,
                          float* __restrict__ Q) {
    int o = blockIdx.x * 256 + threadIdx.x;   // over 1280*192, n-fastest (coalesced reads)
    if (o >= QSZ) return;
    float a = 0.f;
    for (int ks = 0; ks < CKS; ks++) a += partial[(size_t)ks * QSZ + o];
    int n = o % 192, c = o / 192;
    Q[(size_t)n * INDIM + c] = a / (float)max(gcnt[n & 63], 1);
}

// ---------------- generic split-K f32 GEMM for the head ----------------
template <int MT, int K, int N, int NS>
__global__ __launch_bounds__(256) void gemm_sk(const float* __restrict__ A,
                                               const float* __restrict__ W,
                                               float* __restrict__ part) {
    constexpr int KL = K / NS;
    __shared__ float a_s[32][33];
    int tid = threadIdx.x;
    int c = blockIdx.x * 64 + (tid & 63);
    int grp = tid >> 6;
    int m0 = blockIdx.y * 32;
    int k00 = blockIdx.z * KL;
    float acc[8];
#pragma unroll
    for (int i = 0; i < 8; i++) acc[i] = 0.f;
    for (int k0 = k00; k0 < k00 + KL; k0 += 32) {
        __syncthreads();
#pragma unroll
        for (int i = 0; i < 4; i++) {
            int idx = tid + i * 256;
            int row = idx >> 5, kk = idx & 31;
            a_s[row][kk] = A[(size_t)(m0 + row) * K + k0 + kk];
        }
        __syncthreads();
#pragma unroll
        for (int kk = 0; kk < 32; kk++) {
            float w = W[(size_t)(k0 + kk) * N + c];
#pragma unroll
            for (int i = 0; i < 8; i++)
                acc[i] = fmaf(a_s[grp * 8 + i][kk], w, acc[i]);
        }
    }
#pragma unroll
    for (int i = 0; i < 8; i++) {
        int m = m0 + grp * 8 + i;
        part[((size_t)blockIdx.z * MT + m) * N + c] = acc[i];
    }
}

// ---------------- head combine kernels ----------------
__global__ void comb_qh(const float* __restrict__ p, const float* __restrict__ sigraw,
                        const int* __restrict__ gcnt, const float* __restrict__ b1,
                        float* __restrict__ G, float* __restrict__ t2,
                        float* __restrict__ t3) {
    int o = blockIdx.x * 256 + threadIdx.x;
    if (o >= 192 * GD) return;
    float v = 0.f;
#pragma unroll
    for (int ns = 0; ns < 5; ns++) v += p[(size_t)ns * 192 * GD + o];
    int m = o >> 9, c = o & 511;
    float bc = b1[c];
    if (m < 64) {
        G[(size_t)m * CAT + c] = v + bc;
    } else if (m < 128) {
        int g = m - 64;
        t2[(size_t)g * GD + c] = v + (sigraw[g] / (float)max(gcnt[g], 1)) * bc;
    } else {
        int g = m - 128;
        t3[(size_t)g * GD + c] = v + (sigraw[64 + g] / (float)max(gcnt[g], 1)) * bc;
    }
}

__global__ void comb_w2(const float* __restrict__ pA, const float* __restrict__ pB,
                        const float* __restrict__ sigraw, const int* __restrict__ gcnt,
                        const float* __restrict__ b2, float* __restrict__ G,
                        float* __restrict__ u3) {
    int o = blockIdx.x * 256 + threadIdx.x;
    if (o >= NG * GD) return;
    float va = 0.f, vb = 0.f;
#pragma unroll
    for (int ns = 0; ns < 4; ns++) {
        va += pA[(size_t)ns * NG * GD + o];
        vb += pB[(size_t)ns * NG * GD + o];
    }
    int m = o >> 9, c = o & 511;
    float bc = b2[c];
    G[(size_t)m * CAT + GD + c] = va + bc;
    u3[o] = vb + (sigraw[m] / (float)max(gcnt[m], 1)) * bc;
}

__global__ void comb_w3(const float* __restrict__ pC, const float* __restrict__ b3,
                        float* __restrict__ G) {
    int o = blockIdx.x * 256 + threadIdx.x;
    if (o >= NG * GD) return;
    float v = 0.f;
#pragma unroll
    for (int ns = 0; ns < 4; ns++) v += pC[(size_t)ns * NG * GD + o];
    int m = o >> 9, c = o & 511;
    G[(size_t)m * CAT + 2 * GD + c] = v + b3[c];
}

template <int N, int NS, bool RELU>
__global__ void combf(const float* __restrict__ p, const float* __restrict__ bias,
                      float* __restrict__ out) {
    int o = blockIdx.x * 256 + threadIdx.x;
    if (o >= NG * N) return;
    float v = 0.f;
#pragma unroll
    for (int ns = 0; ns < NS; ns++) v += p[(size_t)ns * NG * N + o];
    v += bias[o % N];
    if (RELU) v = fmaxf(v, 0.f);
    out[o] = v;
}

// ---------------- launch ----------------
static inline size_t al256(size_t x) { return (x + 255) & ~(size_t)255; }

extern "C" void kernel_launch(void* const* d_in, const int* in_sizes, int n_in,
                              void* d_out, int out_size, void* d_ws, size_t ws_size,
                              hipStream_t stream) {
    const float* x   = (const float*)d_in[0];
    const int*   ei  = (const int*)d_in[1];
    const int*   bat = (const int*)d_in[2];
    const float* Wg1 = (const float*)d_in[3];
    const float* bg1 = (const float*)d_in[4];
    const float* Wg2 = (const float*)d_in[5];
    const float* bg2 = (const float*)d_in[6];
    const float* Wg3 = (const float*)d_in[7];
    const float* bg3 = (const float*)d_in[8];
    const float* Wr  = (const float*)d_in[9];
    const float* br  = (const float*)d_in[10];
    const float* Wf  = (const float*)d_in[11];
    const float* bf  = (const float*)d_in[12];
    const float* Wo  = (const float*)d_in[13];
    const float* bo  = (const float*)d_in[14];
    float* out = (float*)d_out;

    char* ws = (char*)d_ws;
    size_t off = 0;
    int*   cnt2    = (int*)(ws + off); off += al256(((size_t)2 * NN + 512) * 4);
    int*   row_ptr = (int*)(ws + off); off += al256((size_t)(NN + 1) * 4);
    int*   fill    = (int*)(ws + off); off += al256((size_t)NN * 4);
    float* dinv    = (float*)(ws + off); off += al256((size_t)NN * 4);
    int*   col     = (int*)(ws + off); off += al256((size_t)EE * 4);
    int*   bsum    = (int*)(ws + off); off += al256(64 * 4);
    float* UU      = (float*)(ws + off); off += al256((size_t)NPAD * 192 * 4);
    unsigned short* UTH = (unsigned short*)(ws + off); off += al256((size_t)192 * NPAD * 2);
    unsigned short* UTL = (unsigned short*)(ws + off); off += al256((size_t)192 * NPAD * 2);
    float* partial = (float*)(ws + off); off += al256((size_t)CKS * QSZ * 4);
    float* Q       = (float*)(ws + off); off += al256((size_t)QSZ * 4);
    float* G       = (float*)(ws + off); off += al256((size_t)NG * CAT * 4);
    float* t2      = (float*)(ws + off); off += al256((size_t)NG * GD * 4);
    float* t3      = (float*)(ws + off); off += al256((size_t)NG * GD * 4);
    float* u3      = (float*)(ws + off); off += al256((size_t)NG * GD * 4);
    float* r0      = (float*)(ws + off); off += al256((size_t)NG * FC0D * 4);
    float* r1      = (float*)(ws + off); off += al256((size_t)NG * FC1D * 4);
    float* pQH     = (float*)(ws + off); off += al256((size_t)5 * 192 * GD * 4);
    float* pA      = (float*)(ws + off); off += al256((size_t)4 * NG * GD * 4);
    float* pB      = (float*)(ws + off); off += al256((size_t)4 * NG * GD * 4);
    float* pC      = (float*)(ws + off); off += al256((size_t)4 * NG * GD * 4);
    float* pD      = (float*)(ws + off); off += al256((size_t)6 * NG * FC0D * 4);
    float* pE      = (float*)(ws + off); off += al256((size_t)8 * NG * FC1D * 4);
    float* pF      = (float*)(ws + off); off += al256((size_t)4 * NG * OUTD * 4);
    (void)ws_size; (void)n_in; (void)in_sizes; (void)out_size;

    int*   cnt_s  = cnt2;
    int*   cnt_d  = cnt2 + NN;
    int*   gcnt   = cnt2 + 2 * NN;                  // 64 ints
    float* sigraw = (float*)(cnt2 + 2 * NN + 64);   // 128 floats

    const int nscan = (NN + 1023) / 1024;

    zero_u32<<<dim3((2 * NN + 512 + 255) / 256), 256, 0, stream>>>((uint32_t*)cnt2, 2 * NN + 512);

    hist_edges<<<dim3((EE + 255) / 256), 256, 0, stream>>>(ei, cnt_s, cnt_d);
    batch_bounds<<<dim3(1), 64, 0, stream>>>(bat, gcnt);

    scan1<<<dim3(nscan), 1024, 0, stream>>>(cnt_s, row_ptr, bsum, NN);
    scan2<<<dim3(1), 64, 0, stream>>>(bsum, nscan);
    scan3b<<<dim3(nscan), 1024, 0, stream>>>(row_ptr, bsum, cnt_d, dinv, fill, NN);
    scatter_src<<<dim3((EE + 255) / 256), 256, 0, stream>>>(ei, fill, col);

    // U propagation into packed UU (pads zero-filled)
    dim3 ugrid(NPAD / 4);
    uprop_first<<<ugrid, 256, 0, stream>>>(row_ptr, col, dinv, bat, UU);
    uprop_next<<<ugrid, 256, 0, stream>>>(row_ptr, col, dinv, UU, 0, 1);
    uprop_next<<<ugrid, 256, 0, stream>>>(row_ptr, col, dinv, UU, 1, 2);

    usig_kernel<<<dim3((NN + 511) / 512), 256, 0, stream>>>(UU, sigraw);

    // transpose + split UU -> UUT bf16 hi/lo
    tsplit_uu<<<dim3(NPAD / 32, 192 / 32), 256, 0, stream>>>(UU, UTH, UTL);

    // MFMA contraction + reduce
    contract_mfma<<<dim3(760), 256, 0, stream>>>(x, UTH, UTL, partial);
    reduce_qt<<<dim3((QSZ + 255) / 256), 256, 0, stream>>>(partial, gcnt, Q);

    // head: split-K GEMMs + combines
    gemm_sk<192, INDIM, GD, 5><<<dim3(GD / 64, 6, 5), 256, 0, stream>>>(Q, Wg1, pQH);
    comb_qh<<<dim3((192 * GD + 255) / 256), 256, 0, stream>>>(pQH, sigraw, gcnt, bg1, G, t2, t3);
    gemm_sk<NG, GD, GD, 4><<<dim3(GD / 64, 2, 4), 256, 0, stream>>>(t2, Wg2, pA);
    gemm_sk<NG, GD, GD, 4><<<dim3(GD / 64, 2, 4), 256, 0, stream>>>(t3, Wg2, pB);
    comb_w2<<<dim3((NG * GD + 255) / 256), 256, 0, stream>>>(pA, pB, sigraw, gcnt, bg2, G, u3);
    gemm_sk<NG, GD, GD, 4><<<dim3(GD / 64, 2, 4), 256, 0, stream>>>(u3, Wg3, pC);
    comb_w3<<<dim3((NG * GD + 255) / 256), 256, 0, stream>>>(pC, bg3, G);
    gemm_sk<NG, CAT, FC0D, 6><<<dim3(FC0D / 64, 2, 6), 256, 0, stream>>>(G, Wr, pD);
    combf<FC0D, 6, true><<<dim3((NG * FC0D + 255) / 256), 256, 0, stream>>>(pD, br, r0);
    gemm_sk<NG, FC0D, FC1D, 8><<<dim3(FC1D / 64, 2, 8), 256, 0, stream>>>(r0, Wf, pE);
    combf<FC1D, 8, true><<<dim3((NG * FC1D + 255) / 256), 256, 0, stream>>>(pE, bf, r1);
    gemm_sk<NG, FC1D, OUTD, 4><<<dim3(OUTD / 64, 2, 4), 256, 0, stream>>>(r1, Wo, pF);
    combf<OUTD, 4, false><<<dim3((NG * OUTD + 255) / 256), 256, 0, stream>>>(pF, bo, out);
}